// Round 6
// baseline (139.609 us; speedup 1.0000x reference)
//
#include <hip/hip_runtime.h>
#include <math.h>

// Problem constants (fixed-shape problem)
#define NPTS 8192
#define CCH  128
#define KNN  16
#define BN_RS 0.9999950000374997f   // 1/sqrt(1 + 1e-5)

typedef unsigned long long u64;

// ---------------------------------------------------------------------------
// Kernel P: pack candidate points as float4 (x, y, z, |p|^2)
// ---------------------------------------------------------------------------
__global__ __launch_bounds__(256) void pack_kernel(const float* __restrict__ p,
                                                   float4* __restrict__ c4) {
    const int j = blockIdx.x * 256 + threadIdx.x;
    if (j < NPTS) {
        const float x = p[3 * j + 0], y = p[3 * j + 1], z = p[3 * j + 2];
        c4[j] = make_float4(x, y, z, x * x + y * y + z * z);
    }
}

// ---------------------------------------------------------------------------
// KNN body: sampled-threshold select (R5 algorithm), LDS staging removed
// (candidates are L2-resident: 128 KB), so it shares one dispatch with gemm.
// ---------------------------------------------------------------------------
#define QW    2
#define CAP   104
#define SAMPN 4096

__device__ __forceinline__ u64 bitonic64(u64 v, const int lane) {
    #pragma unroll
    for (int k = 2; k <= 64; k <<= 1) {
        #pragma unroll
        for (int j = k >> 1; j > 0; j >>= 1) {
            const u64  o       = __shfl_xor(v, j);
            const bool takemin = (((lane & j) == 0) == ((lane & k) == 0));
            v = ((o < v) == takemin) ? o : v;
        }
    }
    return v;
}

__device__ __forceinline__ float bitonicf(float v, const int lane) {
    #pragma unroll
    for (int k = 2; k <= 64; k <<= 1) {
        #pragma unroll
        for (int j = k >> 1; j > 0; j >>= 1) {
            const float o      = __shfl_xor(v, j);
            const bool takemin = (((lane & j) == 0) == ((lane & k) == 0));
            v = ((o < v) == takemin) ? o : v;
        }
    }
    return v;
}

__device__ __forceinline__ float make_d2(const float4 c, const float m2x, const float m2y,
                                         const float m2z, const float qb) {
    float d2 = fmaf(m2x, c.x, fmaf(m2y, c.y, fmaf(m2z, c.z, c.w + qb)));
    return fmaxf(d2, 0.0f);
}

__device__ void knn_body(char* smem, const int kbid,
                         const float4* __restrict__ c4,
                         int* __restrict__ oidx, float* __restrict__ od2) {
    u64 (*s_col)[QW][CAP] = (u64 (*)[QW][CAP])smem;          // [4][QW][CAP]
    int* s_cnt = (int*)(smem + 4 * QW * CAP * sizeof(u64));  // [4*QW]

    const int t     = threadIdx.x;
    const int wave  = t >> 6;
    const int lane  = t & 63;
    const int qbase = (kbid * 4 + wave) * QW;

    float m2x[QW], m2y[QW], m2z[QW], qb[QW];
    #pragma unroll
    for (int qi = 0; qi < QW; ++qi) {
        const float4 q = c4[qbase + qi];
        m2x[qi] = -2.0f * q.x;
        m2y[qi] = -2.0f * q.y;
        m2z[qi] = -2.0f * q.z;
        qb[qi]  = q.w;
    }
    if (lane < QW) s_cnt[wave * QW + lane] = 0;
    __syncthreads();

    // ---- phase A: lane minima over first SAMPN candidates ----
    float bd[QW];
    #pragma unroll
    for (int qi = 0; qi < QW; ++qi) bd[qi] = 3.0e38f;

    for (int l = lane; l < SAMPN; l += 128) {
        const float4 c0 = c4[l];
        const float4 c1 = c4[l + 64];
        #pragma unroll
        for (int qi = 0; qi < QW; ++qi) {
            const float d0 = make_d2(c0, m2x[qi], m2y[qi], m2z[qi], qb[qi]);
            const float d1 = make_d2(c1, m2x[qi], m2y[qi], m2z[qi], qb[qi]);
            bd[qi] = fminf(bd[qi], fminf(d0, d1));
        }
    }

    float tauf[QW];
    #pragma unroll
    for (int qi = 0; qi < QW; ++qi) {
        const float s = bitonicf(bd[qi], lane);
        tauf[qi] = __shfl(s, 15);
    }

    // ---- phase B: collect pass straight from global (L2-resident) ----
    for (int l = lane; l < NPTS; l += 128) {
        const float4 c0 = c4[l];
        const float4 c1 = c4[l + 64];
        const int j0 = l, j1 = l + 64;
        #pragma unroll
        for (int qi = 0; qi < QW; ++qi) {
            const float d0 = make_d2(c0, m2x[qi], m2y[qi], m2z[qi], qb[qi]);
            const float d1 = make_d2(c1, m2x[qi], m2y[qi], m2z[qi], qb[qi]);
            if (d0 <= tauf[qi]) {
                const int pos = atomicAdd(&s_cnt[wave * QW + qi], 1);
                if (pos < CAP)
                    s_col[wave][qi][pos] = ((u64)__float_as_uint(d0) << 32) | (u64)(unsigned)j0;
            }
            if (d1 <= tauf[qi]) {
                const int pos = atomicAdd(&s_cnt[wave * QW + qi], 1);
                if (pos < CAP)
                    s_col[wave][qi][pos] = ((u64)__float_as_uint(d1) << 32) | (u64)(unsigned)j1;
            }
        }
    }

    // ---- final select per query ----
    #pragma unroll 1
    for (int qi = 0; qi < QW; ++qi) {
        const int q = qbase + qi;
        int M = s_cnt[wave * QW + qi];

        if (M > CAP) {
            // exact fallback (exercised ~never)
            float fb = 3.0e38f;
            for (int l = lane; l < NPTS; l += 64)
                fb = fminf(fb, make_d2(c4[l], m2x[qi], m2y[qi], m2z[qi], qb[qi]));
            const float s    = bitonicf(fb, lane);
            const float tau2 = __shfl(s, 15);
            if (lane == 0) s_cnt[wave * QW + qi] = 0;
            for (int l = lane; l < NPTS; l += 64) {
                const float d = make_d2(c4[l], m2x[qi], m2y[qi], m2z[qi], qb[qi]);
                if (d <= tau2) {
                    const int pos = atomicAdd(&s_cnt[wave * QW + qi], 1);
                    if (pos < CAP)
                        s_col[wave][qi][pos] = ((u64)__float_as_uint(d) << 32) | (u64)(unsigned)l;
                }
            }
            M = s_cnt[wave * QW + qi];
            if (M > CAP) M = CAP;
        }

        if (M <= 64) {
            u64 v = (lane < M) ? s_col[wave][qi][lane] : ~0ull;
            v = bitonic64(v, lane);
            if (lane < KNN) {
                oidx[q * KNN + lane] = (int)(v & 0xffffffffu);
                od2 [q * KNN + lane] = __uint_as_float((unsigned)(v >> 32));
            }
        } else {
            u64 a = (lane < M) ? s_col[wave][qi][lane] : ~0ull;
            a = bitonic64(a, lane);
            u64 b = (lane + 64 < M) ? s_col[wave][qi][lane + 64] : ~0ull;
            b = bitonic64(b, lane);
            const u64 bs = __shfl(b, lane & 15);
            u64 mv = (lane < 16) ? a : ((lane < 32) ? bs : ~0ull);
            mv = bitonic64(mv, lane);
            if (lane < KNN) {
                oidx[q * KNN + lane] = (int)(mv & 0xffffffffu);
                od2 [q * KNN + lane] = __uint_as_float((unsigned)(mv >> 32));
            }
        }
    }
}

// ---------------------------------------------------------------------------
// GEMM body: one 64x64 fp32 tile of xq/xk/xv = x @ W + b  (R5 algorithm)
// ---------------------------------------------------------------------------
__device__ void gemm_body(char* smem, const int gbid,
                          const float* __restrict__ x,
                          const float* __restrict__ Wq, const float* __restrict__ bq,
                          const float* __restrict__ Wk, const float* __restrict__ bk,
                          const float* __restrict__ Wv, const float* __restrict__ bv,
                          float* __restrict__ xq, float* __restrict__ xk, float* __restrict__ xv) {
    float (*As)[68] = (float (*)[68])smem;
    float (*Bs)[68] = (float (*)[68])(smem + 64 * 68 * sizeof(float));

    const int which = gbid >> 8;          // 0..2
    const int rem   = gbid & 255;
    const float* W    = (which == 0) ? Wq : (which == 1) ? Wk : Wv;
    const float* bias = (which == 0) ? bq : (which == 1) ? bk : bv;
    float*       out  = (which == 0) ? xq : (which == 1) ? xk : xv;

    const int row0 = (rem & 127) * 64;
    const int col0 = (rem >> 7) * 64;

    const int t  = threadIdx.x;
    const int lr = t >> 4;
    const int lc = t & 15;
    const int or0 = (t >> 4) * 4;
    const int oc0 = (t & 15) * 4;

    float acc[4][4] = {};

    for (int kk = 0; kk < CCH; kk += 64) {
        __syncthreads();
        #pragma unroll
        for (int i = 0; i < 4; ++i) {
            const int r = lr + i * 16;
            *(float4*)&As[r][lc * 4] =
                *(const float4*)&x[(size_t)(row0 + r) * CCH + kk + lc * 4];
            *(float4*)&Bs[r][lc * 4] =
                *(const float4*)&W[(size_t)(kk + r) * CCH + col0 + lc * 4];
        }
        __syncthreads();
        #pragma unroll 8
        for (int k = 0; k < 64; ++k) {
            const float a0 = As[or0 + 0][k];
            const float a1 = As[or0 + 1][k];
            const float a2 = As[or0 + 2][k];
            const float a3 = As[or0 + 3][k];
            const float4 b = *(const float4*)&Bs[k][oc0];
            acc[0][0] += a0 * b.x; acc[0][1] += a0 * b.y; acc[0][2] += a0 * b.z; acc[0][3] += a0 * b.w;
            acc[1][0] += a1 * b.x; acc[1][1] += a1 * b.y; acc[1][2] += a1 * b.z; acc[1][3] += a1 * b.w;
            acc[2][0] += a2 * b.x; acc[2][1] += a2 * b.y; acc[2][2] += a2 * b.z; acc[2][3] += a2 * b.w;
            acc[3][0] += a3 * b.x; acc[3][1] += a3 * b.y; acc[3][2] += a3 * b.z; acc[3][3] += a3 * b.w;
        }
    }

    const float4 bb = *(const float4*)&bias[col0 + oc0];
    #pragma unroll
    for (int i = 0; i < 4; ++i) {
        const int r = row0 + or0 + i;
        float4 o;
        o.x = acc[i][0] + bb.x;
        o.y = acc[i][1] + bb.y;
        o.z = acc[i][2] + bb.z;
        o.w = acc[i][3] + bb.w;
        *(float4*)&out[(size_t)r * CCH + col0 + oc0] = o;
    }
}

// ---------------------------------------------------------------------------
// Merged dispatch: 1792 blocks = 1024 knn + 768 gemm, interleaved 4:3 so each
// CU co-schedules VALU-heavy knn waves with memory-heavy gemm waves.
// LDS = max(gemm 34.8 KB, knn 6.7 KB).
// ---------------------------------------------------------------------------
__global__ __launch_bounds__(256) void knn_gemm_kernel(
    const float4* __restrict__ c4, int* __restrict__ oidx, float* __restrict__ od2,
    const float* __restrict__ x,
    const float* __restrict__ Wq, const float* __restrict__ bq,
    const float* __restrict__ Wk, const float* __restrict__ bk,
    const float* __restrict__ Wv, const float* __restrict__ bv,
    float* __restrict__ xq, float* __restrict__ xk, float* __restrict__ xv) {
    __shared__ __align__(16) char smem[2 * 64 * 68 * sizeof(float)];
    const int grp = blockIdx.x / 7;
    const int u   = blockIdx.x % 7;
    if (u < 4) knn_body(smem, grp * 4 + u, c4, oidx, od2);
    else       gemm_body(smem, grp * 3 + (u - 4), x, Wq, bq, Wk, bk, Wv, bv, xq, xk, xv);
}

// ---------------------------------------------------------------------------
// Kernel C: fused per-point attention, v3.  1 block = PPB=8 points.
//  - Ww1 staged to LDS once per block (amortized 8x); Ww2 column + bw1/g3/be3/
//    bw2 scalars hoisted to registers.
//  - val8/wv8 live in registers end-to-end; cross-wave traffic reduced to two
//    tiny LDS rounds per point (s_w2 16x16 softmax, s_part 4x128 k-reduce),
//    parity double-buffered -> 2 barriers/point.
//  - s_r eliminated (16 intra-wave shuffles); s_val/s_e/s_wn eliminated.
//  - Neighbor row gathers software-pipelined one point ahead.
// ---------------------------------------------------------------------------
#define PPB 8

__global__ __launch_bounds__(256) void fused_kernel(
    const float* __restrict__ p,
    const float* __restrict__ xqg, const float* __restrict__ xkg, const float* __restrict__ xvg,
    const int* __restrict__ nidx, const float* __restrict__ nd2,
    const float* __restrict__ Wp1, const float* __restrict__ bp1,
    const float* __restrict__ g1,  const float* __restrict__ be1,
    const float* __restrict__ Wp2, const float* __restrict__ bp2,
    const float* __restrict__ g2,  const float* __restrict__ be2,
    const float* __restrict__ Ww1, const float* __restrict__ bw1,
    const float* __restrict__ g3,  const float* __restrict__ be3,
    const float* __restrict__ Ww2, const float* __restrict__ bw2,
    float* __restrict__ out) {
    const int i0 = blockIdx.x * PPB;
    const int t  = threadIdx.x;

    __shared__ float s_w1tA[16][66];
    __shared__ float s_w1tB[16][66];
    __shared__ float s_w2[2][16][17];
    __shared__ float s_part[2][4][132];

    const int k    = t >> 4;       // neighbor 0..15
    const int tl   = t & 15;       // m / channel-group
    const int c0   = tl * 8;
    const int lane = t & 63;
    const int wq   = t >> 6;       // wave id 0..3

    // ---- hoisted per-thread constants ----
    const float bw1m = bw1[tl];
    const float g3m  = g3[tl] * BN_RS;
    const float be3m = be3[tl];
    const float bw2m = bw2[tl];
    float ww2c[16];
    #pragma unroll
    for (int mm = 0; mm < 16; ++mm) ww2c[mm] = Ww2[mm * 16 + tl];

    // ---- stage Ww1 transposed/split/padded ----
    #pragma unroll
    for (int j = 0; j < 8; ++j) {
        const int e2   = t + j * 256;       // = csrc*16 + m
        const int m    = e2 & 15;
        const int csrc = e2 >> 4;
        const int col  = ((csrc >> 3) << 2) | (csrc & 3);
        const float v  = Ww1[e2];
        if (csrc & 4) s_w1tB[m][col] = v;
        else          s_w1tA[m][col] = v;
    }

    // ---- neighbor ids for all 8 points (prefetch) ----
    int   jn_a[PPB];
    float d2_a[PPB];
    #pragma unroll
    for (int j = 0; j < PPB; ++j) {
        jn_a[j] = nidx[(i0 + j) * KNN + k];
        d2_a[j] = nd2 [(i0 + j) * KNN + k];
    }

    __syncthreads();   // w1t ready

    // ---- software pipeline: rows for point j loaded at end of j-1 ----
    float4 ka0, ka1, kb0, kb1;
    {
        const size_t r = (size_t)jn_a[0] * CCH;
        ka0 = *(const float4*)&xkg[r + c0];
        ka1 = *(const float4*)&xkg[r + c0 + 4];
        kb0 = *(const float4*)&xvg[r + c0];
        kb1 = *(const float4*)&xvg[r + c0 + 4];
    }

    #pragma unroll
    for (int j = 0; j < PPB; ++j) {
        const int i   = i0 + j;
        const int par = j & 1;
        const int jn  = jn_a[j];

        // ---- phase 1: pr + wv/val in registers ----
        const float dw  = expf(-sqrtf(fmaxf(d2_a[j], 0.f)));
        const float prx = p[jn * 3 + 0] - p[i * 3 + 0];
        const float pry = p[jn * 3 + 1] - p[i * 3 + 1];
        const float prz = p[jn * 3 + 2] - p[i * 3 + 2];
        float tt[3];
        #pragma unroll
        for (int e = 0; e < 3; ++e) {
            float v = prx * Wp1[0 * 3 + e] + pry * Wp1[1 * 3 + e] + prz * Wp1[2 * 3 + e] + bp1[e];
            v = v * (g1[e] * BN_RS) + be1[e];
            tt[e] = fmaxf(v, 0.f);
        }

        float wv8[8], val8[8];
        #pragma unroll
        for (int h = 0; h < 2; ++h) {
            const int cc = c0 + h * 4;
            const float4 xk4 = h ? ka1 : ka0;
            const float4 xv4 = h ? kb1 : kb0;
            const float4 w0  = *(const float4*)&Wp2[cc];
            const float4 w1  = *(const float4*)&Wp2[128 + cc];
            const float4 w2  = *(const float4*)&Wp2[256 + cc];
            const float4 bp  = *(const float4*)&bp2[cc];
            const float4 xq4 = *(const float4*)&xqg[(size_t)i * CCH + cc];
            const float4 gg  = *(const float4*)&g2[cc];
            const float4 bb  = *(const float4*)&be2[cc];
            {
                const float pr = tt[0] * w0.x + tt[1] * w1.x + tt[2] * w2.x + bp.x;
                wv8[h * 4 + 0]  = fmaxf(((xq4.x - xk4.x) + pr) * (gg.x * BN_RS) + bb.x, 0.f);
                val8[h * 4 + 0] = xv4.x * dw + pr;
            }
            {
                const float pr = tt[0] * w0.y + tt[1] * w1.y + tt[2] * w2.y + bp.y;
                wv8[h * 4 + 1]  = fmaxf(((xq4.y - xk4.y) + pr) * (gg.y * BN_RS) + bb.y, 0.f);
                val8[h * 4 + 1] = xv4.y * dw + pr;
            }
            {
                const float pr = tt[0] * w0.z + tt[1] * w1.z + tt[2] * w2.z + bp.z;
                wv8[h * 4 + 2]  = fmaxf(((xq4.z - xk4.z) + pr) * (gg.z * BN_RS) + bb.z, 0.f);
                val8[h * 4 + 2] = xv4.z * dw + pr;
            }
            {
                const float pr = tt[0] * w0.w + tt[1] * w1.w + tt[2] * w2.w + bp.w;
                wv8[h * 4 + 3]  = fmaxf(((xq4.w - xk4.w) + pr) * (gg.w * BN_RS) + bb.w, 0.f);
                val8[h * 4 + 3] = xv4.w * dw + pr;
            }
        }

        // ---- issue next point's gathers (hidden under phases 2-4) ----
        if (j + 1 < PPB) {
            const size_t r = (size_t)jn_a[j + 1] * CCH;
            ka0 = *(const float4*)&xkg[r + c0];
            ka1 = *(const float4*)&xkg[r + c0 + 4];
            kb0 = *(const float4*)&xvg[r + c0];
            kb1 = *(const float4*)&xvg[r + c0 + 4];
        }

        // ---- phase 2: all-m partials + butterfly transpose-reduce ----
        float pp[16];
        #pragma unroll
        for (int m = 0; m < 16; ++m) {
            const float4 a = *(const float4*)&s_w1tA[m][tl * 4];
            const float4 b = *(const float4*)&s_w1tB[m][tl * 4];
            pp[m] = wv8[0] * a.x + wv8[1] * a.y + wv8[2] * a.z + wv8[3] * a.w
                  + wv8[4] * b.x + wv8[5] * b.y + wv8[6] * b.z + wv8[7] * b.w;
        }
        float q8[8];
        #pragma unroll
        for (int jj = 0; jj < 8; ++jj) {
            const float send = (tl & 8) ? pp[jj] : pp[jj + 8];
            const float keep = (tl & 8) ? pp[jj + 8] : pp[jj];
            q8[jj] = keep + __shfl_xor(send, 8);
        }
        float q4[4];
        #pragma unroll
        for (int jj = 0; jj < 4; ++jj) {
            const float send = (tl & 4) ? q8[jj] : q8[jj + 4];
            const float keep = (tl & 4) ? q8[jj + 4] : q8[jj];
            q4[jj] = keep + __shfl_xor(send, 4);
        }
        float q2[2];
        #pragma unroll
        for (int jj = 0; jj < 2; ++jj) {
            const float send = (tl & 2) ? q4[jj] : q4[jj + 2];
            const float keep = (tl & 2) ? q4[jj + 2] : q4[jj];
            q2[jj] = keep + __shfl_xor(send, 2);
        }
        const float send1 = (tl & 1) ? q2[0] : q2[1];
        const float keep1 = (tl & 1) ? q2[1] : q2[0];
        const float w1sum = keep1 + __shfl_xor(send1, 1);

        // lane (k, m=tl) holds w1[k][m]
        const float rr = fmaxf((w1sum + bw1m) * g3m + be3m, 0.f);

        // w2[k][m] via intra-wave shuffles over mm (row k lives in this wave)
        float acc2 = bw2m;
        #pragma unroll
        for (int mm = 0; mm < 16; ++mm)
            acc2 += __shfl(rr, (lane & 48) | mm) * ww2c[mm];
        s_w2[par][k][tl] = acc2;
        __syncthreads();

        // ---- phase 3: softmax over k (per-lane redundant, no extra barrier) ----
        float mx = -3.0e38f;
        #pragma unroll
        for (int mm = 0; mm < 16; ++mm) mx = fmaxf(mx, s_w2[par][mm][tl]);
        float ss = 0.f;
        #pragma unroll
        for (int mm = 0; mm < 16; ++mm) ss += expf(s_w2[par][mm][tl] - mx);
        const float wn = expf(acc2 - mx) / ss;

        // ---- phase 4: out from registers via shuffles + k-reduce ----
        float o8[8];
        #pragma unroll
        for (int d = 0; d < 8; ++d) {
            const int srcm = (c0 + d) & 15;
            const float wnd = __shfl(wn, (lane & 48) | srcm);
            o8[d] = val8[d] * wnd;
        }
        #pragma unroll
        for (int d = 0; d < 8; ++d) {
            o8[d] += __shfl_xor(o8[d], 16);
            o8[d] += __shfl_xor(o8[d], 32);
        }
        if ((lane >> 4) == 0) {
            *(float4*)&s_part[par][wq][c0]     = make_float4(o8[0], o8[1], o8[2], o8[3]);
            *(float4*)&s_part[par][wq][c0 + 4] = make_float4(o8[4], o8[5], o8[6], o8[7]);
        }
        __syncthreads();
        if (t < 128) {
            const float o = s_part[par][0][t] + s_part[par][1][t]
                          + s_part[par][2][t] + s_part[par][3][t];
            out[(size_t)i * CCH + t] = o;
        }
    }
}

// ---------------------------------------------------------------------------
extern "C" void kernel_launch(void* const* d_in, const int* in_sizes, int n_in,
                              void* d_out, int out_size, void* d_ws, size_t ws_size,
                              hipStream_t stream) {
    (void)in_sizes; (void)n_in; (void)out_size; (void)ws_size;
    const float* p   = (const float*)d_in[0];
    const float* x   = (const float*)d_in[1];
    const float* Wq  = (const float*)d_in[2];
    const float* bq  = (const float*)d_in[3];
    const float* Wk  = (const float*)d_in[4];
    const float* bk  = (const float*)d_in[5];
    const float* Wv  = (const float*)d_in[6];
    const float* bv  = (const float*)d_in[7];
    const float* Wp1 = (const float*)d_in[8];
    const float* bp1 = (const float*)d_in[9];
    const float* g1  = (const float*)d_in[10];
    const float* be1 = (const float*)d_in[11];
    const float* Wp2 = (const float*)d_in[12];
    const float* bp2 = (const float*)d_in[13];
    const float* g2  = (const float*)d_in[14];
    const float* be2 = (const float*)d_in[15];
    const float* Ww1 = (const float*)d_in[16];
    const float* bw1 = (const float*)d_in[17];
    const float* g3  = (const float*)d_in[18];
    const float* be3 = (const float*)d_in[19];
    const float* Ww2 = (const float*)d_in[20];
    const float* bw2 = (const float*)d_in[21];
    float* out = (float*)d_out;

    // workspace layout
    char* ws = (char*)d_ws;
    int*    idxb = (int*)ws;                                   // 512 KB
    float*  d2b  = (float*)(ws + (size_t)512 * 1024);          // 512 KB
    float*  xqb  = (float*)(ws + (size_t)1 * 1024 * 1024);     // 4 MB
    float*  xkb  = (float*)(ws + (size_t)5 * 1024 * 1024);     // 4 MB
    float*  xvb  = (float*)(ws + (size_t)9 * 1024 * 1024);     // 4 MB
    float4* c4b  = (float4*)(ws + (size_t)13 * 1024 * 1024);   // 128 KB

    pack_kernel<<<dim3(NPTS / 256), dim3(256), 0, stream>>>(p, c4b);
    knn_gemm_kernel<<<dim3(256 * 7), dim3(256), 0, stream>>>(
        c4b, idxb, d2b, x, Wq, bq, Wk, bk, Wv, bv, xqb, xkb, xvb);
    fused_kernel<<<dim3(NPTS / PPB), dim3(256), 0, stream>>>(
        p, xqb, xkb, xvb, idxb, d2b,
        Wp1, bp1, g1, be1, Wp2, bp2, g2, be2, Ww1, bw1, g3, be3, Ww2, bw2, out);
}

// Round 7
// 123.098 us; speedup vs baseline: 1.1341x; 1.1341x over previous
//
#include <hip/hip_runtime.h>
#include <math.h>

// Problem constants (fixed-shape problem)
#define NPTS 8192
#define CCH  128
#define KNN  16
#define BN_RS 0.9999950000374997f   // 1/sqrt(1 + 1e-5)

typedef unsigned long long u64;

// ---------------------------------------------------------------------------
// Kernel P: pack candidate points as float4 (x, y, z, |p|^2)
// ---------------------------------------------------------------------------
__global__ __launch_bounds__(256) void pack_kernel(const float* __restrict__ p,
                                                   float4* __restrict__ c4) {
    const int j = blockIdx.x * 256 + threadIdx.x;
    if (j < NPTS) {
        const float x = p[3 * j + 0], y = p[3 * j + 1], z = p[3 * j + 2];
        c4[j] = make_float4(x, y, z, x * x + y * y + z * z);
    }
}

// ---------------------------------------------------------------------------
// Kernel A: KNN via sampled-threshold 1.25-pass select (R5 version, verbatim —
// R6's merged/unstaged variant regressed: L1 thrash without LDS tiles).
// ---------------------------------------------------------------------------
#define QW    2
#define CAP   104
#define TILE  2048
#define SAMPN 4096

__device__ __forceinline__ u64 bitonic64(u64 v, const int lane) {
    #pragma unroll
    for (int k = 2; k <= 64; k <<= 1) {
        #pragma unroll
        for (int j = k >> 1; j > 0; j >>= 1) {
            const u64  o       = __shfl_xor(v, j);
            const bool takemin = (((lane & j) == 0) == ((lane & k) == 0));
            v = ((o < v) == takemin) ? o : v;
        }
    }
    return v;
}

__device__ __forceinline__ float bitonicf(float v, const int lane) {
    #pragma unroll
    for (int k = 2; k <= 64; k <<= 1) {
        #pragma unroll
        for (int j = k >> 1; j > 0; j >>= 1) {
            const float o      = __shfl_xor(v, j);
            const bool takemin = (((lane & j) == 0) == ((lane & k) == 0));
            v = ((o < v) == takemin) ? o : v;
        }
    }
    return v;
}

__device__ __forceinline__ float make_d2(const float4 c, const float m2x, const float m2y,
                                         const float m2z, const float qb) {
    float d2 = fmaf(m2x, c.x, fmaf(m2y, c.y, fmaf(m2z, c.z, c.w + qb)));
    return fmaxf(d2, 0.0f);
}

__global__ __launch_bounds__(256) void knn_kernel(const float4* __restrict__ c4,
                                                  int* __restrict__ oidx,
                                                  float* __restrict__ od2) {
    __shared__ float4 s_pt[TILE];
    __shared__ u64    s_col[4][QW][CAP];
    __shared__ int    s_cnt[4][QW];

    const int t     = threadIdx.x;
    const int wave  = t >> 6;
    const int lane  = t & 63;
    const int qbase = (blockIdx.x * 4 + wave) * QW;

    float m2x[QW], m2y[QW], m2z[QW], qb[QW];
    #pragma unroll
    for (int qi = 0; qi < QW; ++qi) {
        const float4 q = c4[qbase + qi];
        m2x[qi] = -2.0f * q.x;
        m2y[qi] = -2.0f * q.y;
        m2z[qi] = -2.0f * q.z;
        qb[qi]  = q.w;
    }
    if (lane < QW) s_cnt[wave][lane] = 0;

    float bd[QW];
    #pragma unroll
    for (int qi = 0; qi < QW; ++qi) bd[qi] = 3.0e38f;

    for (int l = lane; l < SAMPN; l += 128) {
        const float4 c0 = c4[l];
        const float4 c1 = c4[l + 64];
        #pragma unroll
        for (int qi = 0; qi < QW; ++qi) {
            const float d0 = make_d2(c0, m2x[qi], m2y[qi], m2z[qi], qb[qi]);
            const float d1 = make_d2(c1, m2x[qi], m2y[qi], m2z[qi], qb[qi]);
            bd[qi] = fminf(bd[qi], fminf(d0, d1));
        }
    }

    float tauf[QW];
    #pragma unroll
    for (int qi = 0; qi < QW; ++qi) {
        const float s = bitonicf(bd[qi], lane);
        tauf[qi] = __shfl(s, 15);
    }

    for (int tb = 0; tb < NPTS; tb += TILE) {
        __syncthreads();
        for (int jj = t; jj < TILE; jj += 256) s_pt[jj] = c4[tb + jj];
        __syncthreads();
        for (int l = lane; l < TILE; l += 128) {
            const float4 c0 = s_pt[l];
            const float4 c1 = s_pt[l + 64];
            const int j0 = tb + l, j1 = tb + l + 64;
            #pragma unroll
            for (int qi = 0; qi < QW; ++qi) {
                const float d0 = make_d2(c0, m2x[qi], m2y[qi], m2z[qi], qb[qi]);
                const float d1 = make_d2(c1, m2x[qi], m2y[qi], m2z[qi], qb[qi]);
                if (d0 <= tauf[qi]) {
                    const int pos = atomicAdd(&s_cnt[wave][qi], 1);
                    if (pos < CAP)
                        s_col[wave][qi][pos] = ((u64)__float_as_uint(d0) << 32) | (u64)(unsigned)j0;
                }
                if (d1 <= tauf[qi]) {
                    const int pos = atomicAdd(&s_cnt[wave][qi], 1);
                    if (pos < CAP)
                        s_col[wave][qi][pos] = ((u64)__float_as_uint(d1) << 32) | (u64)(unsigned)j1;
                }
            }
        }
    }

    #pragma unroll 1
    for (int qi = 0; qi < QW; ++qi) {
        const int q = qbase + qi;
        int M = s_cnt[wave][qi];

        if (M > CAP) {
            float fb = 3.0e38f;
            for (int l = lane; l < NPTS; l += 64)
                fb = fminf(fb, make_d2(c4[l], m2x[qi], m2y[qi], m2z[qi], qb[qi]));
            const float s    = bitonicf(fb, lane);
            const float tau2 = __shfl(s, 15);
            if (lane == 0) s_cnt[wave][qi] = 0;
            for (int l = lane; l < NPTS; l += 64) {
                const float d = make_d2(c4[l], m2x[qi], m2y[qi], m2z[qi], qb[qi]);
                if (d <= tau2) {
                    const int pos = atomicAdd(&s_cnt[wave][qi], 1);
                    if (pos < CAP)
                        s_col[wave][qi][pos] = ((u64)__float_as_uint(d) << 32) | (u64)(unsigned)l;
                }
            }
            M = s_cnt[wave][qi];
            if (M > CAP) M = CAP;
        }

        if (M <= 64) {
            u64 v = (lane < M) ? s_col[wave][qi][lane] : ~0ull;
            v = bitonic64(v, lane);
            if (lane < KNN) {
                oidx[q * KNN + lane] = (int)(v & 0xffffffffu);
                od2 [q * KNN + lane] = __uint_as_float((unsigned)(v >> 32));
            }
        } else {
            u64 a = (lane < M) ? s_col[wave][qi][lane] : ~0ull;
            a = bitonic64(a, lane);
            u64 b = (lane + 64 < M) ? s_col[wave][qi][lane + 64] : ~0ull;
            b = bitonic64(b, lane);
            const u64 bs = __shfl(b, lane & 15);
            u64 mv = (lane < 16) ? a : ((lane < 32) ? bs : ~0ull);
            mv = bitonic64(mv, lane);
            if (lane < KNN) {
                oidx[q * KNN + lane] = (int)(mv & 0xffffffffu);
                od2 [q * KNN + lane] = __uint_as_float((unsigned)(mv >> 32));
            }
        }
    }
}

// ---------------------------------------------------------------------------
// Kernel B: three fp32 GEMMs (R5 version, verbatim).
// ---------------------------------------------------------------------------
__global__ __launch_bounds__(256) void gemm3_kernel(
    const float* __restrict__ x,
    const float* __restrict__ Wq, const float* __restrict__ bq,
    const float* __restrict__ Wk, const float* __restrict__ bk,
    const float* __restrict__ Wv, const float* __restrict__ bv,
    float* __restrict__ xq, float* __restrict__ xk, float* __restrict__ xv) {
    const int which = blockIdx.z;
    const float* W    = (which == 0) ? Wq : (which == 1) ? Wk : Wv;
    const float* bias = (which == 0) ? bq : (which == 1) ? bk : bv;
    float*       out  = (which == 0) ? xq : (which == 1) ? xk : xv;

    const int row0 = blockIdx.x * 64;
    const int col0 = blockIdx.y * 64;

    __shared__ float As[64][68];
    __shared__ float Bs[64][68];

    const int t  = threadIdx.x;
    const int lr = t >> 4;
    const int lc = t & 15;
    const int or0 = (t >> 4) * 4;
    const int oc0 = (t & 15) * 4;

    float acc[4][4] = {};

    for (int kk = 0; kk < CCH; kk += 64) {
        __syncthreads();
        #pragma unroll
        for (int i = 0; i < 4; ++i) {
            const int r = lr + i * 16;
            *(float4*)&As[r][lc * 4] =
                *(const float4*)&x[(size_t)(row0 + r) * CCH + kk + lc * 4];
            *(float4*)&Bs[r][lc * 4] =
                *(const float4*)&W[(size_t)(kk + r) * CCH + col0 + lc * 4];
        }
        __syncthreads();
        #pragma unroll 8
        for (int k = 0; k < 64; ++k) {
            const float a0 = As[or0 + 0][k];
            const float a1 = As[or0 + 1][k];
            const float a2 = As[or0 + 2][k];
            const float a3 = As[or0 + 3][k];
            const float4 b = *(const float4*)&Bs[k][oc0];
            acc[0][0] += a0 * b.x; acc[0][1] += a0 * b.y; acc[0][2] += a0 * b.z; acc[0][3] += a0 * b.w;
            acc[1][0] += a1 * b.x; acc[1][1] += a1 * b.y; acc[1][2] += a1 * b.z; acc[1][3] += a1 * b.w;
            acc[2][0] += a2 * b.x; acc[2][1] += a2 * b.y; acc[2][2] += a2 * b.z; acc[2][3] += a2 * b.w;
            acc[3][0] += a3 * b.x; acc[3][1] += a3 * b.y; acc[3][2] += a3 * b.z; acc[3][3] += a3 * b.w;
        }
    }

    const float4 bb = *(const float4*)&bias[col0 + oc0];
    #pragma unroll
    for (int i = 0; i < 4; ++i) {
        const int r = row0 + or0 + i;
        float4 o;
        o.x = acc[i][0] + bb.x;
        o.y = acc[i][1] + bb.y;
        o.z = acc[i][2] + bb.z;
        o.w = acc[i][3] + bb.w;
        *(float4*)&out[(size_t)r * CCH + col0 + oc0] = o;
    }
}

// ---------------------------------------------------------------------------
// Kernel C: fused per-point attention, v4.  1 block (256 thr) = PPB=8 points.
// v2 skeleton (measured 45.7 us) + amortization:
//  - Ww1 staged to LDS ONCE per 8 points; Ww2 column, Wp2 rows, BN scalars
//    hoisted to registers once.
//  - Per-point: 3 barriers (parity double-buffer on s_val only; s_r/s_w2/s_wn
//    single-buffered — hazard-checked: every read completes >=1 barrier before
//    the next write to the same buffer).
//  - Softmax: per-lane redundant max/sum from s_w2 (removes v2's s_e round).
//  - NO dynamic-lane shuffles (R6 lesson: they compile to ds_bpermute).
//  - Neighbor-row gathers software-pipelined one point ahead.
// ---------------------------------------------------------------------------
#define PPB 8

__global__ __launch_bounds__(256) void fused_kernel(
    const float* __restrict__ p,
    const float* __restrict__ xqg, const float* __restrict__ xkg, const float* __restrict__ xvg,
    const int* __restrict__ nidx, const float* __restrict__ nd2,
    const float* __restrict__ Wp1, const float* __restrict__ bp1,
    const float* __restrict__ g1,  const float* __restrict__ be1,
    const float* __restrict__ Wp2, const float* __restrict__ bp2,
    const float* __restrict__ g2,  const float* __restrict__ be2,
    const float* __restrict__ Ww1, const float* __restrict__ bw1,
    const float* __restrict__ g3,  const float* __restrict__ be3,
    const float* __restrict__ Ww2, const float* __restrict__ bw2,
    float* __restrict__ out) {
    const int i0 = blockIdx.x * PPB;
    const int t  = threadIdx.x;

    __shared__ float s_w1tA[16][66];        // 4.2 KB
    __shared__ float s_w1tB[16][66];        // 4.2 KB
    __shared__ float s_val[2][16][132];     // 16.9 KB (parity double-buffered)
    __shared__ float s_r[16][17], s_w2[16][17], s_wn[16][17];   // 3.2 KB

    const int k  = t >> 4;      // neighbor 0..15
    const int tl = t & 15;      // m / channel-group
    const int c0 = tl * 8;

    // ---- hoisted per-thread constants (point-invariant) ----
    const float bw1m = bw1[tl];
    const float g3m  = g3[tl] * BN_RS;
    const float be3m = be3[tl];
    const float bw2m = bw2[tl];
    float ww2c[16];
    #pragma unroll
    for (int mm = 0; mm < 16; ++mm) ww2c[mm] = Ww2[mm * 16 + tl];

    // Wp1 / BN1 scalars (wave-uniform)
    float wp1r[3][3], bp1r[3], g1r[3], be1r[3];
    #pragma unroll
    for (int e = 0; e < 3; ++e) {
        wp1r[0][e] = Wp1[0 * 3 + e];
        wp1r[1][e] = Wp1[1 * 3 + e];
        wp1r[2][e] = Wp1[2 * 3 + e];
        bp1r[e]    = bp1[e];
        g1r[e]     = g1[e] * BN_RS;
        be1r[e]    = be1[e];
    }

    // Wp2 rows for this thread's channel slice (6 float4 = 24 VGPR)
    const float4 w0A = *(const float4*)&Wp2[c0];
    const float4 w0B = *(const float4*)&Wp2[c0 + 4];
    const float4 w1A = *(const float4*)&Wp2[128 + c0];
    const float4 w1B = *(const float4*)&Wp2[128 + c0 + 4];
    const float4 w2A = *(const float4*)&Wp2[256 + c0];
    const float4 w2B = *(const float4*)&Wp2[256 + c0 + 4];

    // ---- stage Ww1 transposed/split/padded (once per block) ----
    #pragma unroll
    for (int j = 0; j < 8; ++j) {
        const int e2   = t + j * 256;       // = csrc*16 + m
        const int m    = e2 & 15;
        const int csrc = e2 >> 4;
        const int col  = ((csrc >> 3) << 2) | (csrc & 3);
        const float v  = Ww1[e2];
        if (csrc & 4) s_w1tB[m][col] = v;
        else          s_w1tA[m][col] = v;
    }

    // ---- neighbor ids for all 8 points (static-indexed arrays) ----
    int   jn_a[PPB];
    float d2_a[PPB];
    #pragma unroll
    for (int j = 0; j < PPB; ++j) {
        jn_a[j] = nidx[(i0 + j) * KNN + k];
        d2_a[j] = nd2 [(i0 + j) * KNN + k];
    }

    __syncthreads();   // w1t ready (once per block)

    // ---- software pipeline: rows for point j loaded at end of j-1 ----
    float4 ka0, ka1, kb0, kb1;
    {
        const size_t r = (size_t)jn_a[0] * CCH;
        ka0 = *(const float4*)&xkg[r + c0];
        ka1 = *(const float4*)&xkg[r + c0 + 4];
        kb0 = *(const float4*)&xvg[r + c0];
        kb1 = *(const float4*)&xvg[r + c0 + 4];
    }

    #pragma unroll
    for (int j = 0; j < PPB; ++j) {
        const int i   = i0 + j;
        const int par = j & 1;
        const int jn  = jn_a[j];

        // ---- phase 1: pr + wv/val in registers, val -> s_val[par] ----
        const float dw  = expf(-sqrtf(fmaxf(d2_a[j], 0.f)));
        const float prx = p[jn * 3 + 0] - p[i * 3 + 0];
        const float pry = p[jn * 3 + 1] - p[i * 3 + 1];
        const float prz = p[jn * 3 + 2] - p[i * 3 + 2];
        float tt[3];
        #pragma unroll
        for (int e = 0; e < 3; ++e) {
            float v = prx * wp1r[0][e] + pry * wp1r[1][e] + prz * wp1r[2][e] + bp1r[e];
            tt[e] = fmaxf(v * g1r[e] + be1r[e], 0.f);
        }

        float wv8[8];
        #pragma unroll
        for (int h = 0; h < 2; ++h) {
            const int cc = c0 + h * 4;
            const float4 xk4 = h ? ka1 : ka0;
            const float4 xv4 = h ? kb1 : kb0;
            const float4 w0  = h ? w0B : w0A;
            const float4 w1  = h ? w1B : w1A;
            const float4 w2  = h ? w2B : w2A;
            const float4 bp  = *(const float4*)&bp2[cc];
            const float4 xq4 = *(const float4*)&xqg[(size_t)i * CCH + cc];
            const float4 gg  = *(const float4*)&g2[cc];
            const float4 bb  = *(const float4*)&be2[cc];
            float4 val4;
            {
                const float pr = tt[0] * w0.x + tt[1] * w1.x + tt[2] * w2.x + bp.x;
                wv8[h * 4 + 0] = fmaxf(((xq4.x - xk4.x) + pr) * (gg.x * BN_RS) + bb.x, 0.f);
                val4.x = xv4.x * dw + pr;
            }
            {
                const float pr = tt[0] * w0.y + tt[1] * w1.y + tt[2] * w2.y + bp.y;
                wv8[h * 4 + 1] = fmaxf(((xq4.y - xk4.y) + pr) * (gg.y * BN_RS) + bb.y, 0.f);
                val4.y = xv4.y * dw + pr;
            }
            {
                const float pr = tt[0] * w0.z + tt[1] * w1.z + tt[2] * w2.z + bp.z;
                wv8[h * 4 + 2] = fmaxf(((xq4.z - xk4.z) + pr) * (gg.z * BN_RS) + bb.z, 0.f);
                val4.z = xv4.z * dw + pr;
            }
            {
                const float pr = tt[0] * w0.w + tt[1] * w1.w + tt[2] * w2.w + bp.w;
                wv8[h * 4 + 3] = fmaxf(((xq4.w - xk4.w) + pr) * (gg.w * BN_RS) + bb.w, 0.f);
                val4.w = xv4.w * dw + pr;
            }
            *(float4*)&s_val[par][k][cc] = val4;
        }

        // ---- issue next point's gathers (hidden under phases 2-4) ----
        if (j + 1 < PPB) {
            const size_t r = (size_t)jn_a[j + 1] * CCH;
            ka0 = *(const float4*)&xkg[r + c0];
            ka1 = *(const float4*)&xkg[r + c0 + 4];
            kb0 = *(const float4*)&xvg[r + c0];
            kb1 = *(const float4*)&xvg[r + c0 + 4];
        }

        // ---- phase 2: all-m partials + static-xor butterfly transpose-reduce ----
        float pp[16];
        #pragma unroll
        for (int m = 0; m < 16; ++m) {
            const float4 a = *(const float4*)&s_w1tA[m][tl * 4];
            const float4 b = *(const float4*)&s_w1tB[m][tl * 4];
            pp[m] = wv8[0] * a.x + wv8[1] * a.y + wv8[2] * a.z + wv8[3] * a.w
                  + wv8[4] * b.x + wv8[5] * b.y + wv8[6] * b.z + wv8[7] * b.w;
        }
        float q8[8];
        #pragma unroll
        for (int jj = 0; jj < 8; ++jj) {
            const float send = (tl & 8) ? pp[jj] : pp[jj + 8];
            const float keep = (tl & 8) ? pp[jj + 8] : pp[jj];
            q8[jj] = keep + __shfl_xor(send, 8);
        }
        float q4[4];
        #pragma unroll
        for (int jj = 0; jj < 4; ++jj) {
            const float send = (tl & 4) ? q8[jj] : q8[jj + 4];
            const float keep = (tl & 4) ? q8[jj + 4] : q8[jj];
            q4[jj] = keep + __shfl_xor(send, 4);
        }
        float q2[2];
        #pragma unroll
        for (int jj = 0; jj < 2; ++jj) {
            const float send = (tl & 2) ? q2[0] * 0.f + ((tl & 2) ? q4[jj] : q4[jj + 2]) : q4[jj + 2];
            (void)send;
            const float s2 = (tl & 2) ? q4[jj] : q4[jj + 2];
            const float k2 = (tl & 2) ? q4[jj + 2] : q4[jj];
            q2[jj] = k2 + __shfl_xor(s2, 2);
        }
        const float s1 = (tl & 1) ? q2[0] : q2[1];
        const float k1 = (tl & 1) ? q2[1] : q2[0];
        const float w1sum = k1 + __shfl_xor(s1, 1);

        // lane (k, m=tl) holds w1[k][m]
        const float rr = fmaxf((w1sum + bw1m) * g3m + be3m, 0.f);
        s_r[k][tl] = rr;
        __syncthreads();                               // B1

        // ---- phase 2b: w2 = r @ Ww2 (s_r row reads are broadcasts) ----
        float acc2 = bw2m;
        #pragma unroll
        for (int mm = 0; mm < 16; ++mm) acc2 += s_r[k][mm] * ww2c[mm];
        s_w2[k][tl] = acc2;
        __syncthreads();                               // B2

        // ---- phase 3: softmax over k (per-lane redundant; broadcast reads) ----
        float mx = -3.0e38f;
        #pragma unroll
        for (int mm = 0; mm < 16; ++mm) mx = fmaxf(mx, s_w2[mm][tl]);
        float ss = 0.f;
        #pragma unroll
        for (int mm = 0; mm < 16; ++mm) ss += expf(s_w2[mm][tl] - mx);
        s_wn[k][tl] = expf(acc2 - mx) / ss;
        __syncthreads();                               // B3

        // ---- phase 4: out[c] = sum_k val[k][c] * wn[k][c & 15] ----
        if (t < 128) {
            const int c = t, mc = t & 15;
            float o = 0.f;
            #pragma unroll
            for (int kk = 0; kk < 16; ++kk) o += s_val[par][kk][c] * s_wn[kk][mc];
            out[(size_t)i * CCH + c] = o;
        }
    }
}

// ---------------------------------------------------------------------------
extern "C" void kernel_launch(void* const* d_in, const int* in_sizes, int n_in,
                              void* d_out, int out_size, void* d_ws, size_t ws_size,
                              hipStream_t stream) {
    (void)in_sizes; (void)n_in; (void)out_size; (void)ws_size;
    const float* p   = (const float*)d_in[0];
    const float* x   = (const float*)d_in[1];
    const float* Wq  = (const float*)d_in[2];
    const float* bq  = (const float*)d_in[3];
    const float* Wk  = (const float*)d_in[4];
    const float* bk  = (const float*)d_in[5];
    const float* Wv  = (const float*)d_in[6];
    const float* bv  = (const float*)d_in[7];
    const float* Wp1 = (const float*)d_in[8];
    const float* bp1 = (const float*)d_in[9];
    const float* g1  = (const float*)d_in[10];
    const float* be1 = (const float*)d_in[11];
    const float* Wp2 = (const float*)d_in[12];
    const float* bp2 = (const float*)d_in[13];
    const float* g2  = (const float*)d_in[14];
    const float* be2 = (const float*)d_in[15];
    const float* Ww1 = (const float*)d_in[16];
    const float* bw1 = (const float*)d_in[17];
    const float* g3  = (const float*)d_in[18];
    const float* be3 = (const float*)d_in[19];
    const float* Ww2 = (const float*)d_in[20];
    const float* bw2 = (const float*)d_in[21];
    float* out = (float*)d_out;

    // workspace layout
    char* ws = (char*)d_ws;
    int*    idxb = (int*)ws;                                   // 512 KB
    float*  d2b  = (float*)(ws + (size_t)512 * 1024);          // 512 KB
    float*  xqb  = (float*)(ws + (size_t)1 * 1024 * 1024);     // 4 MB
    float*  xkb  = (float*)(ws + (size_t)5 * 1024 * 1024);     // 4 MB
    float*  xvb  = (float*)(ws + (size_t)9 * 1024 * 1024);     // 4 MB
    float4* c4b  = (float4*)(ws + (size_t)13 * 1024 * 1024);   // 128 KB

    pack_kernel<<<dim3(NPTS / 256), dim3(256), 0, stream>>>(p, c4b);
    knn_kernel<<<dim3(NPTS / (4 * QW)), dim3(256), 0, stream>>>(c4b, idxb, d2b);
    gemm3_kernel<<<dim3(NPTS / 64, CCH / 64, 3), dim3(256), 0, stream>>>(
        x, Wq, bq, Wk, bk, Wv, bv, xqb, xkb, xvb);
    fused_kernel<<<dim3(NPTS / PPB), dim3(256), 0, stream>>>(
        p, xqb, xkb, xvb, idxb, d2b,
        Wp1, bp1, g1, be1, Wp2, bp2, g2, be2, Ww1, bw1, g3, be3, Ww2, bw2, out);
}

// Round 8
// 117.036 us; speedup vs baseline: 1.1929x; 1.0518x over previous
//
#include <hip/hip_runtime.h>
#include <math.h>

// Problem constants (fixed-shape problem)
#define NPTS 8192
#define CCH  128
#define KNN  16
#define BN_RS 0.9999950000374997f   // 1/sqrt(1 + 1e-5)

typedef unsigned long long u64;

// ---------------------------------------------------------------------------
// Kernel P: pack candidate points as float4 (x, y, z, |p|^2)
// ---------------------------------------------------------------------------
__global__ __launch_bounds__(256) void pack_kernel(const float* __restrict__ p,
                                                   float4* __restrict__ c4) {
    const int j = blockIdx.x * 256 + threadIdx.x;
    if (j < NPTS) {
        const float x = p[3 * j + 0], y = p[3 * j + 1], z = p[3 * j + 2];
        c4[j] = make_float4(x, y, z, x * x + y * y + z * z);
    }
}

// ---------------------------------------------------------------------------
// KNN body: R5 algorithm VERBATIM (sampled-tau 1.25-pass, LDS tile staging —
// R6 proved removing the staging thrashes L1).  Runs inside the merged kernel.
// ---------------------------------------------------------------------------
#define QW    2
#define CAP   104
#define TILE  2048
#define SAMPN 4096

__device__ __forceinline__ u64 bitonic64(u64 v, const int lane) {
    #pragma unroll
    for (int k = 2; k <= 64; k <<= 1) {
        #pragma unroll
        for (int j = k >> 1; j > 0; j >>= 1) {
            const u64  o       = __shfl_xor(v, j);
            const bool takemin = (((lane & j) == 0) == ((lane & k) == 0));
            v = ((o < v) == takemin) ? o : v;
        }
    }
    return v;
}

__device__ __forceinline__ float bitonicf(float v, const int lane) {
    #pragma unroll
    for (int k = 2; k <= 64; k <<= 1) {
        #pragma unroll
        for (int j = k >> 1; j > 0; j >>= 1) {
            const float o      = __shfl_xor(v, j);
            const bool takemin = (((lane & j) == 0) == ((lane & k) == 0));
            v = ((o < v) == takemin) ? o : v;
        }
    }
    return v;
}

__device__ __forceinline__ float make_d2(const float4 c, const float m2x, const float m2y,
                                         const float m2z, const float qb) {
    float d2 = fmaf(m2x, c.x, fmaf(m2y, c.y, fmaf(m2z, c.z, c.w + qb)));
    return fmaxf(d2, 0.0f);
}

__device__ void knn_body(char* smem, const int kbid,
                         const float4* __restrict__ c4,
                         int* __restrict__ oidx, float* __restrict__ od2) {
    float4* s_pt = (float4*)smem;                                   // 32768 B
    u64 (*s_col)[QW][CAP] = (u64 (*)[QW][CAP])(smem + 32768);       // 6656 B
    int* s_cnt = (int*)(smem + 32768 + 6656);                       // 32 B

    const int t     = threadIdx.x;
    const int wave  = t >> 6;
    const int lane  = t & 63;
    const int qbase = (kbid * 4 + wave) * QW;

    float m2x[QW], m2y[QW], m2z[QW], qb[QW];
    #pragma unroll
    for (int qi = 0; qi < QW; ++qi) {
        const float4 q = c4[qbase + qi];
        m2x[qi] = -2.0f * q.x;
        m2y[qi] = -2.0f * q.y;
        m2z[qi] = -2.0f * q.z;
        qb[qi]  = q.w;
    }
    if (lane < QW) s_cnt[wave * QW + lane] = 0;   // synced by first staging barrier

    float bd[QW];
    #pragma unroll
    for (int qi = 0; qi < QW; ++qi) bd[qi] = 3.0e38f;

    for (int l = lane; l < SAMPN; l += 128) {
        const float4 c0 = c4[l];
        const float4 c1 = c4[l + 64];
        #pragma unroll
        for (int qi = 0; qi < QW; ++qi) {
            const float d0 = make_d2(c0, m2x[qi], m2y[qi], m2z[qi], qb[qi]);
            const float d1 = make_d2(c1, m2x[qi], m2y[qi], m2z[qi], qb[qi]);
            bd[qi] = fminf(bd[qi], fminf(d0, d1));
        }
    }

    float tauf[QW];
    #pragma unroll
    for (int qi = 0; qi < QW; ++qi) {
        const float s = bitonicf(bd[qi], lane);
        tauf[qi] = __shfl(s, 15);
    }

    for (int tb = 0; tb < NPTS; tb += TILE) {
        __syncthreads();
        for (int jj = t; jj < TILE; jj += 256) s_pt[jj] = c4[tb + jj];
        __syncthreads();
        for (int l = lane; l < TILE; l += 128) {
            const float4 c0 = s_pt[l];
            const float4 c1 = s_pt[l + 64];
            const int j0 = tb + l, j1 = tb + l + 64;
            #pragma unroll
            for (int qi = 0; qi < QW; ++qi) {
                const float d0 = make_d2(c0, m2x[qi], m2y[qi], m2z[qi], qb[qi]);
                const float d1 = make_d2(c1, m2x[qi], m2y[qi], m2z[qi], qb[qi]);
                if (d0 <= tauf[qi]) {
                    const int pos = atomicAdd(&s_cnt[wave * QW + qi], 1);
                    if (pos < CAP)
                        s_col[wave][qi][pos] = ((u64)__float_as_uint(d0) << 32) | (u64)(unsigned)j0;
                }
                if (d1 <= tauf[qi]) {
                    const int pos = atomicAdd(&s_cnt[wave * QW + qi], 1);
                    if (pos < CAP)
                        s_col[wave][qi][pos] = ((u64)__float_as_uint(d1) << 32) | (u64)(unsigned)j1;
                }
            }
        }
    }

    #pragma unroll 1
    for (int qi = 0; qi < QW; ++qi) {
        const int q = qbase + qi;
        int M = s_cnt[wave * QW + qi];

        if (M > CAP) {
            // exact fallback (exercised ~never)
            float fb = 3.0e38f;
            for (int l = lane; l < NPTS; l += 64)
                fb = fminf(fb, make_d2(c4[l], m2x[qi], m2y[qi], m2z[qi], qb[qi]));
            const float s    = bitonicf(fb, lane);
            const float tau2 = __shfl(s, 15);
            if (lane == 0) s_cnt[wave * QW + qi] = 0;
            for (int l = lane; l < NPTS; l += 64) {
                const float d = make_d2(c4[l], m2x[qi], m2y[qi], m2z[qi], qb[qi]);
                if (d <= tau2) {
                    const int pos = atomicAdd(&s_cnt[wave * QW + qi], 1);
                    if (pos < CAP)
                        s_col[wave][qi][pos] = ((u64)__float_as_uint(d) << 32) | (u64)(unsigned)l;
                }
            }
            M = s_cnt[wave * QW + qi];
            if (M > CAP) M = CAP;
        }

        if (M <= 64) {
            u64 v = (lane < M) ? s_col[wave][qi][lane] : ~0ull;
            v = bitonic64(v, lane);
            if (lane < KNN) {
                oidx[q * KNN + lane] = (int)(v & 0xffffffffu);
                od2 [q * KNN + lane] = __uint_as_float((unsigned)(v >> 32));
            }
        } else {
            u64 a = (lane < M) ? s_col[wave][qi][lane] : ~0ull;
            a = bitonic64(a, lane);
            u64 b = (lane + 64 < M) ? s_col[wave][qi][lane + 64] : ~0ull;
            b = bitonic64(b, lane);
            const u64 bs = __shfl(b, lane & 15);
            u64 mv = (lane < 16) ? a : ((lane < 32) ? bs : ~0ull);
            mv = bitonic64(mv, lane);
            if (lane < KNN) {
                oidx[q * KNN + lane] = (int)(mv & 0xffffffffu);
                od2 [q * KNN + lane] = __uint_as_float((unsigned)(mv >> 32));
            }
        }
    }
}

// ---------------------------------------------------------------------------
// GEMM body: R5 gemm3 VERBATIM, one 64x64 tile of xq/xk/xv = x @ W + b.
// ---------------------------------------------------------------------------
__device__ void gemm_body(char* smem, const int gbid,
                          const float* __restrict__ x,
                          const float* __restrict__ Wq, const float* __restrict__ bq,
                          const float* __restrict__ Wk, const float* __restrict__ bk,
                          const float* __restrict__ Wv, const float* __restrict__ bv,
                          float* __restrict__ xq, float* __restrict__ xk, float* __restrict__ xv) {
    float (*As)[68] = (float (*)[68])smem;
    float (*Bs)[68] = (float (*)[68])(smem + 64 * 68 * sizeof(float));

    const int which = gbid >> 8;          // 0..2
    const int rem   = gbid & 255;
    const float* W    = (which == 0) ? Wq : (which == 1) ? Wk : Wv;
    const float* bias = (which == 0) ? bq : (which == 1) ? bk : bv;
    float*       out  = (which == 0) ? xq : (which == 1) ? xk : xv;

    const int row0 = (rem & 127) * 64;
    const int col0 = (rem >> 7) * 64;

    const int t  = threadIdx.x;
    const int lr = t >> 4;
    const int lc = t & 15;
    const int or0 = (t >> 4) * 4;
    const int oc0 = (t & 15) * 4;

    float acc[4][4] = {};

    for (int kk = 0; kk < CCH; kk += 64) {
        __syncthreads();
        #pragma unroll
        for (int i = 0; i < 4; ++i) {
            const int r = lr + i * 16;
            *(float4*)&As[r][lc * 4] =
                *(const float4*)&x[(size_t)(row0 + r) * CCH + kk + lc * 4];
            *(float4*)&Bs[r][lc * 4] =
                *(const float4*)&W[(size_t)(kk + r) * CCH + col0 + lc * 4];
        }
        __syncthreads();
        #pragma unroll 8
        for (int k = 0; k < 64; ++k) {
            const float a0 = As[or0 + 0][k];
            const float a1 = As[or0 + 1][k];
            const float a2 = As[or0 + 2][k];
            const float a3 = As[or0 + 3][k];
            const float4 b = *(const float4*)&Bs[k][oc0];
            acc[0][0] += a0 * b.x; acc[0][1] += a0 * b.y; acc[0][2] += a0 * b.z; acc[0][3] += a0 * b.w;
            acc[1][0] += a1 * b.x; acc[1][1] += a1 * b.y; acc[1][2] += a1 * b.z; acc[1][3] += a1 * b.w;
            acc[2][0] += a2 * b.x; acc[2][1] += a2 * b.y; acc[2][2] += a2 * b.z; acc[2][3] += a2 * b.w;
            acc[3][0] += a3 * b.x; acc[3][1] += a3 * b.y; acc[3][2] += a3 * b.z; acc[3][3] += a3 * b.w;
        }
    }

    const float4 bb = *(const float4*)&bias[col0 + oc0];
    #pragma unroll
    for (int i = 0; i < 4; ++i) {
        const int r = row0 + or0 + i;
        float4 o;
        o.x = acc[i][0] + bb.x;
        o.y = acc[i][1] + bb.y;
        o.z = acc[i][2] + bb.z;
        o.w = acc[i][3] + bb.w;
        *(float4*)&out[(size_t)r * CCH + col0 + oc0] = o;
    }
}

// ---------------------------------------------------------------------------
// Merged dispatch: 1792 blocks = 1024 knn + 768 gemm, 4:3 interleave.
// Union LDS 39456 B -> 4 blocks/CU (same as each kernel solo).
// ---------------------------------------------------------------------------
__global__ __launch_bounds__(256) void knn_gemm_kernel(
    const float4* __restrict__ c4, int* __restrict__ oidx, float* __restrict__ od2,
    const float* __restrict__ x,
    const float* __restrict__ Wq, const float* __restrict__ bq,
    const float* __restrict__ Wk, const float* __restrict__ bk,
    const float* __restrict__ Wv, const float* __restrict__ bv,
    float* __restrict__ xq, float* __restrict__ xk, float* __restrict__ xv) {
    __shared__ __align__(16) char smem[39456];
    const int grp = blockIdx.x / 7;
    const int u   = blockIdx.x % 7;
    if (u < 4) knn_body(smem, grp * 4 + u, c4, oidx, od2);
    else       gemm_body(smem, grp * 3 + (u - 4), x, Wq, bq, Wk, bk, Wv, bv, xq, xk, xv);
}

// ---------------------------------------------------------------------------
// Kernel C: fused per-point attention, v5.  1 block (256 thr) = 1 point
// (8192 blocks — occupancy preserved; R7's PPB=8 grid collapse reverted).
// v2 skeleton with TWO LDS rounds removed:
//  - s_r round + barrier -> second static-xor butterfly (lane tl holds
//    r[k][tl]; Ww2 ROW tl hoisted to 16 VGPRs).
//  - s_e round + barrier -> per-lane redundant softmax (validated in R7).
// Barriers/point: 5 -> 3.  LDS 18.6 KB, VGPR ~60.
// ---------------------------------------------------------------------------
__global__ __launch_bounds__(256) void fused_kernel(
    const float* __restrict__ p,
    const float* __restrict__ xqg, const float* __restrict__ xkg, const float* __restrict__ xvg,
    const int* __restrict__ nidx, const float* __restrict__ nd2,
    const float* __restrict__ Wp1, const float* __restrict__ bp1,
    const float* __restrict__ g1,  const float* __restrict__ be1,
    const float* __restrict__ Wp2, const float* __restrict__ bp2,
    const float* __restrict__ g2,  const float* __restrict__ be2,
    const float* __restrict__ Ww1, const float* __restrict__ bw1,
    const float* __restrict__ g3,  const float* __restrict__ be3,
    const float* __restrict__ Ww2, const float* __restrict__ bw2,
    float* __restrict__ out) {
    const int i = blockIdx.x;
    const int t = threadIdx.x;

    __shared__ float s_w1tA[16][66];   // 4.2 KB
    __shared__ float s_w1tB[16][66];   // 4.2 KB
    __shared__ float s_val[16][132];   // 8.4 KB
    __shared__ float s_w2[16][17];     // 1.1 KB
    __shared__ float s_wn[16][17];     // 1.1 KB

    const int k  = t >> 4;      // neighbor 0..15
    const int tl = t & 15;      // m / channel-group
    const int c0 = tl * 8;

    // ---- issue long-latency loads first ----
    const int   jn  = nidx[i * KNN + k];
    const float d2v = nd2[i * KNN + k];
    const float4 a0 = *(const float4*)&xkg[(size_t)jn * CCH + c0];
    const float4 a1 = *(const float4*)&xkg[(size_t)jn * CCH + c0 + 4];
    const float4 b0 = *(const float4*)&xvg[(size_t)jn * CCH + c0];
    const float4 b1 = *(const float4*)&xvg[(size_t)jn * CCH + c0 + 4];

    // Ww2 ROW tl (contribution weights of m=tl to every m2) + scalars
    float ww2row[16];
    #pragma unroll
    for (int j2 = 0; j2 < 16; ++j2) ww2row[j2] = Ww2[tl * 16 + j2];
    const float bw1m = bw1[tl];
    const float g3m  = g3[tl] * BN_RS;
    const float be3m = be3[tl];
    const float bw2m = bw2[tl];

    // ---- stage Ww1 transposed/split/padded ----
    #pragma unroll
    for (int j = 0; j < 8; ++j) {
        const int e2   = t + j * 256;       // = csrc*16 + m
        const int m    = e2 & 15;
        const int csrc = e2 >> 4;
        const int col  = ((csrc >> 3) << 2) | (csrc & 3);
        const float v  = Ww1[e2];
        if (csrc & 4) s_w1tB[m][col] = v;
        else          s_w1tA[m][col] = v;
    }

    // ---- phase 1: pr + wv (regs) + val (LDS) ----
    const float dw  = expf(-sqrtf(fmaxf(d2v, 0.f)));
    const float prx = p[jn * 3 + 0] - p[i * 3 + 0];
    const float pry = p[jn * 3 + 1] - p[i * 3 + 1];
    const float prz = p[jn * 3 + 2] - p[i * 3 + 2];
    float tt[3];
    #pragma unroll
    for (int e = 0; e < 3; ++e) {
        float v = prx * Wp1[0 * 3 + e] + pry * Wp1[1 * 3 + e] + prz * Wp1[2 * 3 + e] + bp1[e];
        v = v * (g1[e] * BN_RS) + be1[e];
        tt[e] = fmaxf(v, 0.f);
    }

    float wv8[8];
    #pragma unroll
    for (int h = 0; h < 2; ++h) {
        const int cc = c0 + h * 4;
        const float4 xk4 = h ? a1 : a0;
        const float4 xv4 = h ? b1 : b0;
        const float4 w0  = *(const float4*)&Wp2[cc];
        const float4 w1  = *(const float4*)&Wp2[128 + cc];
        const float4 w2  = *(const float4*)&Wp2[256 + cc];
        const float4 bp  = *(const float4*)&bp2[cc];
        const float4 xq4 = *(const float4*)&xqg[(size_t)i * CCH + cc];
        const float4 gg  = *(const float4*)&g2[cc];
        const float4 bb  = *(const float4*)&be2[cc];
        float4 val4;
        {
            const float pr = tt[0] * w0.x + tt[1] * w1.x + tt[2] * w2.x + bp.x;
            wv8[h * 4 + 0] = fmaxf(((xq4.x - xk4.x) + pr) * (gg.x * BN_RS) + bb.x, 0.f);
            val4.x = xv4.x * dw + pr;
        }
        {
            const float pr = tt[0] * w0.y + tt[1] * w1.y + tt[2] * w2.y + bp.y;
            wv8[h * 4 + 1] = fmaxf(((xq4.y - xk4.y) + pr) * (gg.y * BN_RS) + bb.y, 0.f);
            val4.y = xv4.y * dw + pr;
        }
        {
            const float pr = tt[0] * w0.z + tt[1] * w1.z + tt[2] * w2.z + bp.z;
            wv8[h * 4 + 2] = fmaxf(((xq4.z - xk4.z) + pr) * (gg.z * BN_RS) + bb.z, 0.f);
            val4.z = xv4.z * dw + pr;
        }
        {
            const float pr = tt[0] * w0.w + tt[1] * w1.w + tt[2] * w2.w + bp.w;
            wv8[h * 4 + 3] = fmaxf(((xq4.w - xk4.w) + pr) * (gg.w * BN_RS) + bb.w, 0.f);
            val4.w = xv4.w * dw + pr;
        }
        *(float4*)&s_val[k][cc] = val4;
    }
    __syncthreads();                                   // B0: w1t + s_val ready

    // ---- phase 2: all-m partials + butterfly #1 (c-reduce/transpose) ----
    float pp[16];
    #pragma unroll
    for (int m = 0; m < 16; ++m) {
        const float4 a = *(const float4*)&s_w1tA[m][tl * 4];
        const float4 b = *(const float4*)&s_w1tB[m][tl * 4];
        pp[m] = wv8[0] * a.x + wv8[1] * a.y + wv8[2] * a.z + wv8[3] * a.w
              + wv8[4] * b.x + wv8[5] * b.y + wv8[6] * b.z + wv8[7] * b.w;
    }
    {
        float q8[8];
        #pragma unroll
        for (int jj = 0; jj < 8; ++jj) {
            const float send = (tl & 8) ? pp[jj] : pp[jj + 8];
            const float keep = (tl & 8) ? pp[jj + 8] : pp[jj];
            q8[jj] = keep + __shfl_xor(send, 8);
        }
        float q4[4];
        #pragma unroll
        for (int jj = 0; jj < 4; ++jj) {
            const float send = (tl & 4) ? q8[jj] : q8[jj + 4];
            const float keep = (tl & 4) ? q8[jj + 4] : q8[jj];
            q4[jj] = keep + __shfl_xor(send, 4);
        }
        float q2[2];
        #pragma unroll
        for (int jj = 0; jj < 2; ++jj) {
            const float send = (tl & 2) ? q4[jj] : q4[jj + 2];
            const float keep = (tl & 2) ? q4[jj + 2] : q4[jj];
            q2[jj] = keep + __shfl_xor(send, 2);
        }
        const float s1 = (tl & 1) ? q2[0] : q2[1];
        const float k1 = (tl & 1) ? q2[1] : q2[0];
        pp[0] = k1 + __shfl_xor(s1, 1);        // w1[k][m=tl]
    }

    // bn + relu at m=tl
    const float rr = fmaxf((pp[0] + bw1m) * g3m + be3m, 0.f);

    // ---- butterfly #2: w2[k][m2] = sum_m rr(m)*Ww2[m][m2], no LDS round ----
    float p2[16];
    #pragma unroll
    for (int j2 = 0; j2 < 16; ++j2) p2[j2] = rr * ww2row[j2];
    float w2v;
    {
        float q8[8];
        #pragma unroll
        for (int jj = 0; jj < 8; ++jj) {
            const float send = (tl & 8) ? p2[jj] : p2[jj + 8];
            const float keep = (tl & 8) ? p2[jj + 8] : p2[jj];
            q8[jj] = keep + __shfl_xor(send, 8);
        }
        float q4[4];
        #pragma unroll
        for (int jj = 0; jj < 4; ++jj) {
            const float send = (tl & 4) ? q8[jj] : q8[jj + 4];
            const float keep = (tl & 4) ? q8[jj + 4] : q8[jj];
            q4[jj] = keep + __shfl_xor(send, 4);
        }
        float q2[2];
        #pragma unroll
        for (int jj = 0; jj < 2; ++jj) {
            const float send = (tl & 2) ? q4[jj] : q4[jj + 2];
            const float keep = (tl & 2) ? q4[jj + 2] : q4[jj];
            q2[jj] = keep + __shfl_xor(send, 2);
        }
        const float s1 = (tl & 1) ? q2[0] : q2[1];
        const float k1 = (tl & 1) ? q2[1] : q2[0];
        w2v = k1 + __shfl_xor(s1, 1) + bw2m;   // w2[k][m2=tl]
    }
    s_w2[k][tl] = w2v;
    __syncthreads();                                   // B1

    // ---- phase 3: softmax over k (per-lane redundant; broadcast reads) ----
    float mx = -3.0e38f;
    #pragma unroll
    for (int mm = 0; mm < 16; ++mm) mx = fmaxf(mx, s_w2[mm][tl]);
    float ss = 0.f;
    #pragma unroll
    for (int mm = 0; mm < 16; ++mm) ss += expf(s_w2[mm][tl] - mx);
    s_wn[k][tl] = expf(w2v - mx) / ss;
    __syncthreads();                                   // B2

    // ---- phase 4: out[c] = sum_k val[k][c] * wn[k][c & 15] ----
    if (t < 128) {
        const int c = t, mc = t & 15;
        float o = 0.f;
        #pragma unroll
        for (int kk = 0; kk < 16; ++kk) o += s_val[kk][c] * s_wn[kk][mc];
        out[(size_t)i * CCH + c] = o;
    }
}

// ---------------------------------------------------------------------------
extern "C" void kernel_launch(void* const* d_in, const int* in_sizes, int n_in,
                              void* d_out, int out_size, void* d_ws, size_t ws_size,
                              hipStream_t stream) {
    (void)in_sizes; (void)n_in; (void)out_size; (void)ws_size;
    const float* p   = (const float*)d_in[0];
    const float* x   = (const float*)d_in[1];
    const float* Wq  = (const float*)d_in[2];
    const float* bq  = (const float*)d_in[3];
    const float* Wk  = (const float*)d_in[4];
    const float* bk  = (const float*)d_in[5];
    const float* Wv  = (const float*)d_in[6];
    const float* bv  = (const float*)d_in[7];
    const float* Wp1 = (const float*)d_in[8];
    const float* bp1 = (const float*)d_in[9];
    const float* g1  = (const float*)d_in[10];
    const float* be1 = (const float*)d_in[11];
    const float* Wp2 = (const float*)d_in[12];
    const float* bp2 = (const float*)d_in[13];
    const float* g2  = (const float*)d_in[14];
    const float* be2 = (const float*)d_in[15];
    const float* Ww1 = (const float*)d_in[16];
    const float* bw1 = (const float*)d_in[17];
    const float* g3  = (const float*)d_in[18];
    const float* be3 = (const float*)d_in[19];
    const float* Ww2 = (const float*)d_in[20];
    const float* bw2 = (const float*)d_in[21];
    float* out = (float*)d_out;

    // workspace layout
    char* ws = (char*)d_ws;
    int*    idxb = (int*)ws;                                   // 512 KB
    float*  d2b  = (float*)(ws + (size_t)512 * 1024);          // 512 KB
    float*  xqb  = (float*)(ws + (size_t)1 * 1024 * 1024);     // 4 MB
    float*  xkb  = (float*)(ws + (size_t)5 * 1024 * 1024);     // 4 MB
    float*  xvb  = (float*)(ws + (size_t)9 * 1024 * 1024);     // 4 MB
    float4* c4b  = (float4*)(ws + (size_t)13 * 1024 * 1024);   // 128 KB

    pack_kernel<<<dim3(NPTS / 256), dim3(256), 0, stream>>>(p, c4b);
    knn_gemm_kernel<<<dim3(256 * 7), dim3(256), 0, stream>>>(
        c4b, idxb, d2b, x, Wq, bq, Wk, bk, Wv, bv, xqb, xkb, xvb);
    fused_kernel<<<dim3(NPTS), dim3(256), 0, stream>>>(
        p, xqb, xkb, xvb, idxb, d2b,
        Wp1, bp1, g1, be1, Wp2, bp2, g2, be2, Ww1, bw1, g3, be3, Ww2, bw2, out);
}

// Round 9
// 112.417 us; speedup vs baseline: 1.2419x; 1.0411x over previous
//
#include <hip/hip_runtime.h>
#include <math.h>

// Problem constants (fixed-shape problem)
#define NPTS 8192
#define CCH  128
#define KNN  16
#define BN_RS 0.9999950000374997f   // 1/sqrt(1 + 1e-5)

typedef unsigned long long u64;

// ---------------------------------------------------------------------------
// Kernel P: pack candidate points as float4 (x, y, z, |p|^2)
// ---------------------------------------------------------------------------
__global__ __launch_bounds__(256) void pack_kernel(const float* __restrict__ p,
                                                   float4* __restrict__ c4) {
    const int j = blockIdx.x * 256 + threadIdx.x;
    if (j < NPTS) {
        const float x = p[3 * j + 0], y = p[3 * j + 1], z = p[3 * j + 2];
        c4[j] = make_float4(x, y, z, x * x + y * y + z * z);
    }
}

// ---------------------------------------------------------------------------
// Kernel A: KNN via sampled-threshold 1.25-pass select.
// R5 algorithm; TILE 2048 -> 1024 so LDS/block = 16.4+6.7 KB -> 7 blocks/CU
// (28 waves/CU, 87% occupancy cap) instead of 4 (16 waves, 50%).
// knn was 60 us at 36% occupancy, latency-bound -> more waves, not less work.
// ---------------------------------------------------------------------------
#define QW    2
#define CAP   104
#define TILE  1024
#define SAMPN 4096

__device__ __forceinline__ u64 bitonic64(u64 v, const int lane) {
    #pragma unroll
    for (int k = 2; k <= 64; k <<= 1) {
        #pragma unroll
        for (int j = k >> 1; j > 0; j >>= 1) {
            const u64  o       = __shfl_xor(v, j);
            const bool takemin = (((lane & j) == 0) == ((lane & k) == 0));
            v = ((o < v) == takemin) ? o : v;
        }
    }
    return v;
}

__device__ __forceinline__ float bitonicf(float v, const int lane) {
    #pragma unroll
    for (int k = 2; k <= 64; k <<= 1) {
        #pragma unroll
        for (int j = k >> 1; j > 0; j >>= 1) {
            const float o      = __shfl_xor(v, j);
            const bool takemin = (((lane & j) == 0) == ((lane & k) == 0));
            v = ((o < v) == takemin) ? o : v;
        }
    }
    return v;
}

__device__ __forceinline__ float make_d2(const float4 c, const float m2x, const float m2y,
                                         const float m2z, const float qb) {
    float d2 = fmaf(m2x, c.x, fmaf(m2y, c.y, fmaf(m2z, c.z, c.w + qb)));
    return fmaxf(d2, 0.0f);
}

__global__ __launch_bounds__(256) void knn_kernel(const float4* __restrict__ c4,
                                                  int* __restrict__ oidx,
                                                  float* __restrict__ od2) {
    __shared__ float4 s_pt[TILE];            // 16 KB
    __shared__ u64    s_col[4][QW][CAP];     // 6.5 KB
    __shared__ int    s_cnt[4][QW];

    const int t     = threadIdx.x;
    const int wave  = t >> 6;
    const int lane  = t & 63;
    const int qbase = (blockIdx.x * 4 + wave) * QW;

    float m2x[QW], m2y[QW], m2z[QW], qb[QW];
    #pragma unroll
    for (int qi = 0; qi < QW; ++qi) {
        const float4 q = c4[qbase + qi];
        m2x[qi] = -2.0f * q.x;
        m2y[qi] = -2.0f * q.y;
        m2z[qi] = -2.0f * q.z;
        qb[qi]  = q.w;
    }
    if (lane < QW) s_cnt[wave][lane] = 0;   // synced by first staging barrier

    // ---- phase A: lane minima over first SAMPN candidates (global/L2) ----
    float bd[QW];
    #pragma unroll
    for (int qi = 0; qi < QW; ++qi) bd[qi] = 3.0e38f;

    for (int l = lane; l < SAMPN; l += 128) {
        const float4 c0 = c4[l];
        const float4 c1 = c4[l + 64];
        #pragma unroll
        for (int qi = 0; qi < QW; ++qi) {
            const float d0 = make_d2(c0, m2x[qi], m2y[qi], m2z[qi], qb[qi]);
            const float d1 = make_d2(c1, m2x[qi], m2y[qi], m2z[qi], qb[qi]);
            bd[qi] = fminf(bd[qi], fminf(d0, d1));
        }
    }

    float tauf[QW];
    #pragma unroll
    for (int qi = 0; qi < QW; ++qi) {
        const float s = bitonicf(bd[qi], lane);
        tauf[qi] = __shfl(s, 15);
    }

    // ---- phase B: collect pass over LDS tiles ----
    for (int tb = 0; tb < NPTS; tb += TILE) {
        __syncthreads();
        for (int jj = t; jj < TILE; jj += 256) s_pt[jj] = c4[tb + jj];
        __syncthreads();
        for (int l = lane; l < TILE; l += 128) {
            const float4 c0 = s_pt[l];
            const float4 c1 = s_pt[l + 64];
            const int j0 = tb + l, j1 = tb + l + 64;
            #pragma unroll
            for (int qi = 0; qi < QW; ++qi) {
                const float d0 = make_d2(c0, m2x[qi], m2y[qi], m2z[qi], qb[qi]);
                const float d1 = make_d2(c1, m2x[qi], m2y[qi], m2z[qi], qb[qi]);
                if (d0 <= tauf[qi]) {
                    const int pos = atomicAdd(&s_cnt[wave][qi], 1);
                    if (pos < CAP)
                        s_col[wave][qi][pos] = ((u64)__float_as_uint(d0) << 32) | (u64)(unsigned)j0;
                }
                if (d1 <= tauf[qi]) {
                    const int pos = atomicAdd(&s_cnt[wave][qi], 1);
                    if (pos < CAP)
                        s_col[wave][qi][pos] = ((u64)__float_as_uint(d1) << 32) | (u64)(unsigned)j1;
                }
            }
        }
    }

    // ---- final select per query ----
    #pragma unroll 1
    for (int qi = 0; qi < QW; ++qi) {
        const int q = qbase + qi;
        int M = s_cnt[wave][qi];

        if (M > CAP) {
            // exact fallback (exercised ~never)
            float fb = 3.0e38f;
            for (int l = lane; l < NPTS; l += 64)
                fb = fminf(fb, make_d2(c4[l], m2x[qi], m2y[qi], m2z[qi], qb[qi]));
            const float s    = bitonicf(fb, lane);
            const float tau2 = __shfl(s, 15);
            if (lane == 0) s_cnt[wave][qi] = 0;
            for (int l = lane; l < NPTS; l += 64) {
                const float d = make_d2(c4[l], m2x[qi], m2y[qi], m2z[qi], qb[qi]);
                if (d <= tau2) {
                    const int pos = atomicAdd(&s_cnt[wave][qi], 1);
                    if (pos < CAP)
                        s_col[wave][qi][pos] = ((u64)__float_as_uint(d) << 32) | (u64)(unsigned)l;
                }
            }
            M = s_cnt[wave][qi];
            if (M > CAP) M = CAP;
        }

        if (M <= 64) {
            u64 v = (lane < M) ? s_col[wave][qi][lane] : ~0ull;
            v = bitonic64(v, lane);
            if (lane < KNN) {
                oidx[q * KNN + lane] = (int)(v & 0xffffffffu);
                od2 [q * KNN + lane] = __uint_as_float((unsigned)(v >> 32));
            }
        } else {
            u64 a = (lane < M) ? s_col[wave][qi][lane] : ~0ull;
            a = bitonic64(a, lane);
            u64 b = (lane + 64 < M) ? s_col[wave][qi][lane + 64] : ~0ull;
            b = bitonic64(b, lane);
            const u64 bs = __shfl(b, lane & 15);
            u64 mv = (lane < 16) ? a : ((lane < 32) ? bs : ~0ull);
            mv = bitonic64(mv, lane);
            if (lane < KNN) {
                oidx[q * KNN + lane] = (int)(mv & 0xffffffffu);
                od2 [q * KNN + lane] = __uint_as_float((unsigned)(mv >> 32));
            }
        }
    }
}

// ---------------------------------------------------------------------------
// Kernel B: three fp32 GEMMs (R5 version, verbatim).
// ---------------------------------------------------------------------------
__global__ __launch_bounds__(256) void gemm3_kernel(
    const float* __restrict__ x,
    const float* __restrict__ Wq, const float* __restrict__ bq,
    const float* __restrict__ Wk, const float* __restrict__ bk,
    const float* __restrict__ Wv, const float* __restrict__ bv,
    float* __restrict__ xq, float* __restrict__ xk, float* __restrict__ xv) {
    const int which = blockIdx.z;
    const float* W    = (which == 0) ? Wq : (which == 1) ? Wk : Wv;
    const float* bias = (which == 0) ? bq : (which == 1) ? bk : bv;
    float*       out  = (which == 0) ? xq : (which == 1) ? xk : xv;

    const int row0 = blockIdx.x * 64;
    const int col0 = blockIdx.y * 64;

    __shared__ float As[64][68];
    __shared__ float Bs[64][68];

    const int t  = threadIdx.x;
    const int lr = t >> 4;
    const int lc = t & 15;
    const int or0 = (t >> 4) * 4;
    const int oc0 = (t & 15) * 4;

    float acc[4][4] = {};

    for (int kk = 0; kk < CCH; kk += 64) {
        __syncthreads();
        #pragma unroll
        for (int i = 0; i < 4; ++i) {
            const int r = lr + i * 16;
            *(float4*)&As[r][lc * 4] =
                *(const float4*)&x[(size_t)(row0 + r) * CCH + kk + lc * 4];
            *(float4*)&Bs[r][lc * 4] =
                *(const float4*)&W[(size_t)(kk + r) * CCH + col0 + lc * 4];
        }
        __syncthreads();
        #pragma unroll 8
        for (int k = 0; k < 64; ++k) {
            const float a0 = As[or0 + 0][k];
            const float a1 = As[or0 + 1][k];
            const float a2 = As[or0 + 2][k];
            const float a3 = As[or0 + 3][k];
            const float4 b = *(const float4*)&Bs[k][oc0];
            acc[0][0] += a0 * b.x; acc[0][1] += a0 * b.y; acc[0][2] += a0 * b.z; acc[0][3] += a0 * b.w;
            acc[1][0] += a1 * b.x; acc[1][1] += a1 * b.y; acc[1][2] += a1 * b.z; acc[1][3] += a1 * b.w;
            acc[2][0] += a2 * b.x; acc[2][1] += a2 * b.y; acc[2][2] += a2 * b.z; acc[2][3] += a2 * b.w;
            acc[3][0] += a3 * b.x; acc[3][1] += a3 * b.y; acc[3][2] += a3 * b.z; acc[3][3] += a3 * b.w;
        }
    }

    const float4 bb = *(const float4*)&bias[col0 + oc0];
    #pragma unroll
    for (int i = 0; i < 4; ++i) {
        const int r = row0 + or0 + i;
        float4 o;
        o.x = acc[i][0] + bb.x;
        o.y = acc[i][1] + bb.y;
        o.z = acc[i][2] + bb.z;
        o.w = acc[i][3] + bb.w;
        *(float4*)&out[(size_t)r * CCH + col0 + oc0] = o;
    }
}

// ---------------------------------------------------------------------------
// Kernel C: fused per-point attention, v5 (R8 version, verbatim — best fused
// so far at ~43 us).  1 block = 1 point; 3 barriers; two in-register
// butterflies; per-lane redundant softmax.
// ---------------------------------------------------------------------------
__global__ __launch_bounds__(256) void fused_kernel(
    const float* __restrict__ p,
    const float* __restrict__ xqg, const float* __restrict__ xkg, const float* __restrict__ xvg,
    const int* __restrict__ nidx, const float* __restrict__ nd2,
    const float* __restrict__ Wp1, const float* __restrict__ bp1,
    const float* __restrict__ g1,  const float* __restrict__ be1,
    const float* __restrict__ Wp2, const float* __restrict__ bp2,
    const float* __restrict__ g2,  const float* __restrict__ be2,
    const float* __restrict__ Ww1, const float* __restrict__ bw1,
    const float* __restrict__ g3,  const float* __restrict__ be3,
    const float* __restrict__ Ww2, const float* __restrict__ bw2,
    float* __restrict__ out) {
    const int i = blockIdx.x;
    const int t = threadIdx.x;

    __shared__ float s_w1tA[16][66];
    __shared__ float s_w1tB[16][66];
    __shared__ float s_val[16][132];
    __shared__ float s_w2[16][17];
    __shared__ float s_wn[16][17];

    const int k  = t >> 4;
    const int tl = t & 15;
    const int c0 = tl * 8;

    // ---- issue long-latency loads first ----
    const int   jn  = nidx[i * KNN + k];
    const float d2v = nd2[i * KNN + k];
    const float4 a0 = *(const float4*)&xkg[(size_t)jn * CCH + c0];
    const float4 a1 = *(const float4*)&xkg[(size_t)jn * CCH + c0 + 4];
    const float4 b0 = *(const float4*)&xvg[(size_t)jn * CCH + c0];
    const float4 b1 = *(const float4*)&xvg[(size_t)jn * CCH + c0 + 4];

    float ww2row[16];
    #pragma unroll
    for (int j2 = 0; j2 < 16; ++j2) ww2row[j2] = Ww2[tl * 16 + j2];
    const float bw1m = bw1[tl];
    const float g3m  = g3[tl] * BN_RS;
    const float be3m = be3[tl];
    const float bw2m = bw2[tl];

    #pragma unroll
    for (int j = 0; j < 8; ++j) {
        const int e2   = t + j * 256;
        const int m    = e2 & 15;
        const int csrc = e2 >> 4;
        const int col  = ((csrc >> 3) << 2) | (csrc & 3);
        const float v  = Ww1[e2];
        if (csrc & 4) s_w1tB[m][col] = v;
        else          s_w1tA[m][col] = v;
    }

    const float dw  = expf(-sqrtf(fmaxf(d2v, 0.f)));
    const float prx = p[jn * 3 + 0] - p[i * 3 + 0];
    const float pry = p[jn * 3 + 1] - p[i * 3 + 1];
    const float prz = p[jn * 3 + 2] - p[i * 3 + 2];
    float tt[3];
    #pragma unroll
    for (int e = 0; e < 3; ++e) {
        float v = prx * Wp1[0 * 3 + e] + pry * Wp1[1 * 3 + e] + prz * Wp1[2 * 3 + e] + bp1[e];
        v = v * (g1[e] * BN_RS) + be1[e];
        tt[e] = fmaxf(v, 0.f);
    }

    float wv8[8];
    #pragma unroll
    for (int h = 0; h < 2; ++h) {
        const int cc = c0 + h * 4;
        const float4 xk4 = h ? a1 : a0;
        const float4 xv4 = h ? b1 : b0;
        const float4 w0  = *(const float4*)&Wp2[cc];
        const float4 w1  = *(const float4*)&Wp2[128 + cc];
        const float4 w2  = *(const float4*)&Wp2[256 + cc];
        const float4 bp  = *(const float4*)&bp2[cc];
        const float4 xq4 = *(const float4*)&xqg[(size_t)i * CCH + cc];
        const float4 gg  = *(const float4*)&g2[cc];
        const float4 bb  = *(const float4*)&be2[cc];
        float4 val4;
        {
            const float pr = tt[0] * w0.x + tt[1] * w1.x + tt[2] * w2.x + bp.x;
            wv8[h * 4 + 0] = fmaxf(((xq4.x - xk4.x) + pr) * (gg.x * BN_RS) + bb.x, 0.f);
            val4.x = xv4.x * dw + pr;
        }
        {
            const float pr = tt[0] * w0.y + tt[1] * w1.y + tt[2] * w2.y + bp.y;
            wv8[h * 4 + 1] = fmaxf(((xq4.y - xk4.y) + pr) * (gg.y * BN_RS) + bb.y, 0.f);
            val4.y = xv4.y * dw + pr;
        }
        {
            const float pr = tt[0] * w0.z + tt[1] * w1.z + tt[2] * w2.z + bp.z;
            wv8[h * 4 + 2] = fmaxf(((xq4.z - xk4.z) + pr) * (gg.z * BN_RS) + bb.z, 0.f);
            val4.z = xv4.z * dw + pr;
        }
        {
            const float pr = tt[0] * w0.w + tt[1] * w1.w + tt[2] * w2.w + bp.w;
            wv8[h * 4 + 3] = fmaxf(((xq4.w - xk4.w) + pr) * (gg.w * BN_RS) + bb.w, 0.f);
            val4.w = xv4.w * dw + pr;
        }
        *(float4*)&s_val[k][cc] = val4;
    }
    __syncthreads();                                   // B0

    float pp[16];
    #pragma unroll
    for (int m = 0; m < 16; ++m) {
        const float4 a = *(const float4*)&s_w1tA[m][tl * 4];
        const float4 b = *(const float4*)&s_w1tB[m][tl * 4];
        pp[m] = wv8[0] * a.x + wv8[1] * a.y + wv8[2] * a.z + wv8[3] * a.w
              + wv8[4] * b.x + wv8[5] * b.y + wv8[6] * b.z + wv8[7] * b.w;
    }
    {
        float q8[8];
        #pragma unroll
        for (int jj = 0; jj < 8; ++jj) {
            const float send = (tl & 8) ? pp[jj] : pp[jj + 8];
            const float keep = (tl & 8) ? pp[jj + 8] : pp[jj];
            q8[jj] = keep + __shfl_xor(send, 8);
        }
        float q4[4];
        #pragma unroll
        for (int jj = 0; jj < 4; ++jj) {
            const float send = (tl & 4) ? q8[jj] : q8[jj + 4];
            const float keep = (tl & 4) ? q8[jj + 4] : q8[jj];
            q4[jj] = keep + __shfl_xor(send, 4);
        }
        float q2[2];
        #pragma unroll
        for (int jj = 0; jj < 2; ++jj) {
            const float send = (tl & 2) ? q4[jj] : q4[jj + 2];
            const float keep = (tl & 2) ? q4[jj + 2] : q4[jj];
            q2[jj] = keep + __shfl_xor(send, 2);
        }
        const float s1 = (tl & 1) ? q2[0] : q2[1];
        const float k1 = (tl & 1) ? q2[1] : q2[0];
        pp[0] = k1 + __shfl_xor(s1, 1);        // w1[k][m=tl]
    }

    const float rr = fmaxf((pp[0] + bw1m) * g3m + be3m, 0.f);

    float p2[16];
    #pragma unroll
    for (int j2 = 0; j2 < 16; ++j2) p2[j2] = rr * ww2row[j2];
    float w2v;
    {
        float q8[8];
        #pragma unroll
        for (int jj = 0; jj < 8; ++jj) {
            const float send = (tl & 8) ? p2[jj] : p2[jj + 8];
            const float keep = (tl & 8) ? p2[jj + 8] : p2[jj];
            q8[jj] = keep + __shfl_xor(send, 8);
        }
        float q4[4];
        #pragma unroll
        for (int jj = 0; jj < 4; ++jj) {
            const float send = (tl & 4) ? q8[jj] : q8[jj + 4];
            const float keep = (tl & 4) ? q8[jj + 4] : q8[jj];
            q4[jj] = keep + __shfl_xor(send, 4);
        }
        float q2[2];
        #pragma unroll
        for (int jj = 0; jj < 2; ++jj) {
            const float send = (tl & 2) ? q4[jj] : q4[jj + 2];
            const float keep = (tl & 2) ? q4[jj + 2] : q4[jj];
            q2[jj] = keep + __shfl_xor(send, 2);
        }
        const float s1 = (tl & 1) ? q2[0] : q2[1];
        const float k1 = (tl & 1) ? q2[1] : q2[0];
        w2v = k1 + __shfl_xor(s1, 1) + bw2m;   // w2[k][m2=tl]
    }
    s_w2[k][tl] = w2v;
    __syncthreads();                                   // B1

    float mx = -3.0e38f;
    #pragma unroll
    for (int mm = 0; mm < 16; ++mm) mx = fmaxf(mx, s_w2[mm][tl]);
    float ss = 0.f;
    #pragma unroll
    for (int mm = 0; mm < 16; ++mm) ss += expf(s_w2[mm][tl] - mx);
    s_wn[k][tl] = expf(w2v - mx) / ss;
    __syncthreads();                                   // B2

    if (t < 128) {
        const int c = t, mc = t & 15;
        float o = 0.f;
        #pragma unroll
        for (int kk = 0; kk < 16; ++kk) o += s_val[kk][c] * s_wn[kk][mc];
        out[(size_t)i * CCH + c] = o;
    }
}

// ---------------------------------------------------------------------------
extern "C" void kernel_launch(void* const* d_in, const int* in_sizes, int n_in,
                              void* d_out, int out_size, void* d_ws, size_t ws_size,
                              hipStream_t stream) {
    (void)in_sizes; (void)n_in; (void)out_size; (void)ws_size;
    const float* p   = (const float*)d_in[0];
    const float* x   = (const float*)d_in[1];
    const float* Wq  = (const float*)d_in[2];
    const float* bq  = (const float*)d_in[3];
    const float* Wk  = (const float*)d_in[4];
    const float* bk  = (const float*)d_in[5];
    const float* Wv  = (const float*)d_in[6];
    const float* bv  = (const float*)d_in[7];
    const float* Wp1 = (const float*)d_in[8];
    const float* bp1 = (const float*)d_in[9];
    const float* g1  = (const float*)d_in[10];
    const float* be1 = (const float*)d_in[11];
    const float* Wp2 = (const float*)d_in[12];
    const float* bp2 = (const float*)d_in[13];
    const float* g2  = (const float*)d_in[14];
    const float* be2 = (const float*)d_in[15];
    const float* Ww1 = (const float*)d_in[16];
    const float* bw1 = (const float*)d_in[17];
    const float* g3  = (const float*)d_in[18];
    const float* be3 = (const float*)d_in[19];
    const float* Ww2 = (const float*)d_in[20];
    const float* bw2 = (const float*)d_in[21];
    float* out = (float*)d_out;

    // workspace layout
    char* ws = (char*)d_ws;
    int*    idxb = (int*)ws;                                   // 512 KB
    float*  d2b  = (float*)(ws + (size_t)512 * 1024);          // 512 KB
    float*  xqb  = (float*)(ws + (size_t)1 * 1024 * 1024);     // 4 MB
    float*  xkb  = (float*)(ws + (size_t)5 * 1024 * 1024);     // 4 MB
    float*  xvb  = (float*)(ws + (size_t)9 * 1024 * 1024);     // 4 MB
    float4* c4b  = (float4*)(ws + (size_t)13 * 1024 * 1024);   // 128 KB

    pack_kernel<<<dim3(NPTS / 256), dim3(256), 0, stream>>>(p, c4b);
    knn_kernel<<<dim3(NPTS / (4 * QW)), dim3(256), 0, stream>>>(c4b, idxb, d2b);
    gemm3_kernel<<<dim3(NPTS / 64, CCH / 64, 3), dim3(256), 0, stream>>>(
        x, Wq, bq, Wk, bk, Wv, bv, xqb, xkb, xvb);
    fused_kernel<<<dim3(NPTS), dim3(256), 0, stream>>>(
        p, xqb, xkb, xvb, idxb, d2b,
        Wp1, bp1, g1, be1, Wp2, bp2, g2, be2, Ww1, bw1, g3, be3, Ww2, bw2, out);
}

// Round 10
// 110.747 us; speedup vs baseline: 1.2606x; 1.0151x over previous
//
#include <hip/hip_runtime.h>
#include <math.h>

// Problem constants (fixed-shape problem)
#define NPTS 8192
#define CCH  128
#define KNN  16
#define BN_RS 0.9999950000374997f   // 1/sqrt(1 + 1e-5)

typedef unsigned long long u64;

// ---------------------------------------------------------------------------
// Kernel P: pack candidate points as float4 (x, y, z, |p|^2)
// ---------------------------------------------------------------------------
__global__ __launch_bounds__(256) void pack_kernel(const float* __restrict__ p,
                                                   float4* __restrict__ c4) {
    const int j = blockIdx.x * 256 + threadIdx.x;
    if (j < NPTS) {
        const float x = p[3 * j + 0], y = p[3 * j + 1], z = p[3 * j + 2];
        c4[j] = make_float4(x, y, z, x * x + y * y + z * z);
    }
}

// ---------------------------------------------------------------------------
// Kernel A: KNN via sampled-threshold 1.25-pass select (R9 version, verbatim).
// ---------------------------------------------------------------------------
#define QW    2
#define CAP   104
#define TILE  1024
#define SAMPN 4096

__device__ __forceinline__ u64 bitonic64(u64 v, const int lane) {
    #pragma unroll
    for (int k = 2; k <= 64; k <<= 1) {
        #pragma unroll
        for (int j = k >> 1; j > 0; j >>= 1) {
            const u64  o       = __shfl_xor(v, j);
            const bool takemin = (((lane & j) == 0) == ((lane & k) == 0));
            v = ((o < v) == takemin) ? o : v;
        }
    }
    return v;
}

__device__ __forceinline__ float bitonicf(float v, const int lane) {
    #pragma unroll
    for (int k = 2; k <= 64; k <<= 1) {
        #pragma unroll
        for (int j = k >> 1; j > 0; j >>= 1) {
            const float o      = __shfl_xor(v, j);
            const bool takemin = (((lane & j) == 0) == ((lane & k) == 0));
            v = ((o < v) == takemin) ? o : v;
        }
    }
    return v;
}

__device__ __forceinline__ float make_d2(const float4 c, const float m2x, const float m2y,
                                         const float m2z, const float qb) {
    float d2 = fmaf(m2x, c.x, fmaf(m2y, c.y, fmaf(m2z, c.z, c.w + qb)));
    return fmaxf(d2, 0.0f);
}

__global__ __launch_bounds__(256) void knn_kernel(const float4* __restrict__ c4,
                                                  int* __restrict__ oidx,
                                                  float* __restrict__ od2) {
    __shared__ float4 s_pt[TILE];            // 16 KB
    __shared__ u64    s_col[4][QW][CAP];     // 6.5 KB
    __shared__ int    s_cnt[4][QW];

    const int t     = threadIdx.x;
    const int wave  = t >> 6;
    const int lane  = t & 63;
    const int qbase = (blockIdx.x * 4 + wave) * QW;

    float m2x[QW], m2y[QW], m2z[QW], qb[QW];
    #pragma unroll
    for (int qi = 0; qi < QW; ++qi) {
        const float4 q = c4[qbase + qi];
        m2x[qi] = -2.0f * q.x;
        m2y[qi] = -2.0f * q.y;
        m2z[qi] = -2.0f * q.z;
        qb[qi]  = q.w;
    }
    if (lane < QW) s_cnt[wave][lane] = 0;   // synced by first staging barrier

    // ---- phase A: lane minima over first SAMPN candidates (global/L2) ----
    float bd[QW];
    #pragma unroll
    for (int qi = 0; qi < QW; ++qi) bd[qi] = 3.0e38f;

    for (int l = lane; l < SAMPN; l += 128) {
        const float4 c0 = c4[l];
        const float4 c1 = c4[l + 64];
        #pragma unroll
        for (int qi = 0; qi < QW; ++qi) {
            const float d0 = make_d2(c0, m2x[qi], m2y[qi], m2z[qi], qb[qi]);
            const float d1 = make_d2(c1, m2x[qi], m2y[qi], m2z[qi], qb[qi]);
            bd[qi] = fminf(bd[qi], fminf(d0, d1));
        }
    }

    float tauf[QW];
    #pragma unroll
    for (int qi = 0; qi < QW; ++qi) {
        const float s = bitonicf(bd[qi], lane);
        tauf[qi] = __shfl(s, 15);
    }

    // ---- phase B: collect pass over LDS tiles ----
    for (int tb = 0; tb < NPTS; tb += TILE) {
        __syncthreads();
        for (int jj = t; jj < TILE; jj += 256) s_pt[jj] = c4[tb + jj];
        __syncthreads();
        for (int l = lane; l < TILE; l += 128) {
            const float4 c0 = s_pt[l];
            const float4 c1 = s_pt[l + 64];
            const int j0 = tb + l, j1 = tb + l + 64;
            #pragma unroll
            for (int qi = 0; qi < QW; ++qi) {
                const float d0 = make_d2(c0, m2x[qi], m2y[qi], m2z[qi], qb[qi]);
                const float d1 = make_d2(c1, m2x[qi], m2y[qi], m2z[qi], qb[qi]);
                if (d0 <= tauf[qi]) {
                    const int pos = atomicAdd(&s_cnt[wave][qi], 1);
                    if (pos < CAP)
                        s_col[wave][qi][pos] = ((u64)__float_as_uint(d0) << 32) | (u64)(unsigned)j0;
                }
                if (d1 <= tauf[qi]) {
                    const int pos = atomicAdd(&s_cnt[wave][qi], 1);
                    if (pos < CAP)
                        s_col[wave][qi][pos] = ((u64)__float_as_uint(d1) << 32) | (u64)(unsigned)j1;
                }
            }
        }
    }

    // ---- final select per query ----
    #pragma unroll 1
    for (int qi = 0; qi < QW; ++qi) {
        const int q = qbase + qi;
        int M = s_cnt[wave][qi];

        if (M > CAP) {
            // exact fallback (exercised ~never)
            float fb = 3.0e38f;
            for (int l = lane; l < NPTS; l += 64)
                fb = fminf(fb, make_d2(c4[l], m2x[qi], m2y[qi], m2z[qi], qb[qi]));
            const float s    = bitonicf(fb, lane);
            const float tau2 = __shfl(s, 15);
            if (lane == 0) s_cnt[wave][qi] = 0;
            for (int l = lane; l < NPTS; l += 64) {
                const float d = make_d2(c4[l], m2x[qi], m2y[qi], m2z[qi], qb[qi]);
                if (d <= tau2) {
                    const int pos = atomicAdd(&s_cnt[wave][qi], 1);
                    if (pos < CAP)
                        s_col[wave][qi][pos] = ((u64)__float_as_uint(d) << 32) | (u64)(unsigned)l;
                }
            }
            M = s_cnt[wave][qi];
            if (M > CAP) M = CAP;
        }

        if (M <= 64) {
            u64 v = (lane < M) ? s_col[wave][qi][lane] : ~0ull;
            v = bitonic64(v, lane);
            if (lane < KNN) {
                oidx[q * KNN + lane] = (int)(v & 0xffffffffu);
                od2 [q * KNN + lane] = __uint_as_float((unsigned)(v >> 32));
            }
        } else {
            u64 a = (lane < M) ? s_col[wave][qi][lane] : ~0ull;
            a = bitonic64(a, lane);
            u64 b = (lane + 64 < M) ? s_col[wave][qi][lane + 64] : ~0ull;
            b = bitonic64(b, lane);
            const u64 bs = __shfl(b, lane & 15);
            u64 mv = (lane < 16) ? a : ((lane < 32) ? bs : ~0ull);
            mv = bitonic64(mv, lane);
            if (lane < KNN) {
                oidx[q * KNN + lane] = (int)(mv & 0xffffffffu);
                od2 [q * KNN + lane] = __uint_as_float((unsigned)(mv >> 32));
            }
        }
    }
}

// ---------------------------------------------------------------------------
// Kernel B: three fp32 GEMMs (R5 version, verbatim).
// ---------------------------------------------------------------------------
__global__ __launch_bounds__(256) void gemm3_kernel(
    const float* __restrict__ x,
    const float* __restrict__ Wq, const float* __restrict__ bq,
    const float* __restrict__ Wk, const float* __restrict__ bk,
    const float* __restrict__ Wv, const float* __restrict__ bv,
    float* __restrict__ xq, float* __restrict__ xk, float* __restrict__ xv) {
    const int which = blockIdx.z;
    const float* W    = (which == 0) ? Wq : (which == 1) ? Wk : Wv;
    const float* bias = (which == 0) ? bq : (which == 1) ? bk : bv;
    float*       out  = (which == 0) ? xq : (which == 1) ? xk : xv;

    const int row0 = blockIdx.x * 64;
    const int col0 = blockIdx.y * 64;

    __shared__ float As[64][68];
    __shared__ float Bs[64][68];

    const int t  = threadIdx.x;
    const int lr = t >> 4;
    const int lc = t & 15;
    const int or0 = (t >> 4) * 4;
    const int oc0 = (t & 15) * 4;

    float acc[4][4] = {};

    for (int kk = 0; kk < CCH; kk += 64) {
        __syncthreads();
        #pragma unroll
        for (int i = 0; i < 4; ++i) {
            const int r = lr + i * 16;
            *(float4*)&As[r][lc * 4] =
                *(const float4*)&x[(size_t)(row0 + r) * CCH + kk + lc * 4];
            *(float4*)&Bs[r][lc * 4] =
                *(const float4*)&W[(size_t)(kk + r) * CCH + col0 + lc * 4];
        }
        __syncthreads();
        #pragma unroll 8
        for (int k = 0; k < 64; ++k) {
            const float a0 = As[or0 + 0][k];
            const float a1 = As[or0 + 1][k];
            const float a2 = As[or0 + 2][k];
            const float a3 = As[or0 + 3][k];
            const float4 b = *(const float4*)&Bs[k][oc0];
            acc[0][0] += a0 * b.x; acc[0][1] += a0 * b.y; acc[0][2] += a0 * b.z; acc[0][3] += a0 * b.w;
            acc[1][0] += a1 * b.x; acc[1][1] += a1 * b.y; acc[1][2] += a1 * b.z; acc[1][3] += a1 * b.w;
            acc[2][0] += a2 * b.x; acc[2][1] += a2 * b.y; acc[2][2] += a2 * b.z; acc[2][3] += a2 * b.w;
            acc[3][0] += a3 * b.x; acc[3][1] += a3 * b.y; acc[3][2] += a3 * b.z; acc[3][3] += a3 * b.w;
        }
    }

    const float4 bb = *(const float4*)&bias[col0 + oc0];
    #pragma unroll
    for (int i = 0; i < 4; ++i) {
        const int r = row0 + or0 + i;
        float4 o;
        o.x = acc[i][0] + bb.x;
        o.y = acc[i][1] + bb.y;
        o.z = acc[i][2] + bb.z;
        o.w = acc[i][3] + bb.w;
        *(float4*)&out[(size_t)r * CCH + col0 + oc0] = o;
    }
}

// ---------------------------------------------------------------------------
// Kernel C: fused per-point attention, v6 = v5 + fast transcendentals.
// v5 was VALU-issue bound (VALUBusy 88%): libm expf ~8-12 instr x 17 calls per
// thread was ~25% of the instruction stream.  __expf = 2 instr (mul + v_exp),
// __fdividef for the softmax divide.  ww2row via 4 float4 loads.
// Everything else identical to v5 (measured 47.4 us).
// ---------------------------------------------------------------------------
__global__ __launch_bounds__(256) void fused_kernel(
    const float* __restrict__ p,
    const float* __restrict__ xqg, const float* __restrict__ xkg, const float* __restrict__ xvg,
    const int* __restrict__ nidx, const float* __restrict__ nd2,
    const float* __restrict__ Wp1, const float* __restrict__ bp1,
    const float* __restrict__ g1,  const float* __restrict__ be1,
    const float* __restrict__ Wp2, const float* __restrict__ bp2,
    const float* __restrict__ g2,  const float* __restrict__ be2,
    const float* __restrict__ Ww1, const float* __restrict__ bw1,
    const float* __restrict__ g3,  const float* __restrict__ be3,
    const float* __restrict__ Ww2, const float* __restrict__ bw2,
    float* __restrict__ out) {
    const int i = blockIdx.x;
    const int t = threadIdx.x;

    __shared__ float s_w1tA[16][66];
    __shared__ float s_w1tB[16][66];
    __shared__ float s_val[16][132];
    __shared__ float s_w2[16][17];
    __shared__ float s_wn[16][17];

    const int k  = t >> 4;
    const int tl = t & 15;
    const int c0 = tl * 8;

    // ---- issue long-latency loads first ----
    const int   jn  = nidx[i * KNN + k];
    const float d2v = nd2[i * KNN + k];
    const float4 a0 = *(const float4*)&xkg[(size_t)jn * CCH + c0];
    const float4 a1 = *(const float4*)&xkg[(size_t)jn * CCH + c0 + 4];
    const float4 b0 = *(const float4*)&xvg[(size_t)jn * CCH + c0];
    const float4 b1 = *(const float4*)&xvg[(size_t)jn * CCH + c0 + 4];

    // Ww2 ROW tl via vector loads (contiguous)
    float ww2row[16];
    {
        const float4 r0 = *(const float4*)&Ww2[tl * 16 + 0];
        const float4 r1 = *(const float4*)&Ww2[tl * 16 + 4];
        const float4 r2 = *(const float4*)&Ww2[tl * 16 + 8];
        const float4 r3 = *(const float4*)&Ww2[tl * 16 + 12];
        ww2row[0]=r0.x; ww2row[1]=r0.y; ww2row[2]=r0.z; ww2row[3]=r0.w;
        ww2row[4]=r1.x; ww2row[5]=r1.y; ww2row[6]=r1.z; ww2row[7]=r1.w;
        ww2row[8]=r2.x; ww2row[9]=r2.y; ww2row[10]=r2.z; ww2row[11]=r2.w;
        ww2row[12]=r3.x; ww2row[13]=r3.y; ww2row[14]=r3.z; ww2row[15]=r3.w;
    }
    const float bw1m = bw1[tl];
    const float g3m  = g3[tl] * BN_RS;
    const float be3m = be3[tl];
    const float bw2m = bw2[tl];

    #pragma unroll
    for (int j = 0; j < 8; ++j) {
        const int e2   = t + j * 256;
        const int m    = e2 & 15;
        const int csrc = e2 >> 4;
        const int col  = ((csrc >> 3) << 2) | (csrc & 3);
        const float v  = Ww1[e2];
        if (csrc & 4) s_w1tB[m][col] = v;
        else          s_w1tA[m][col] = v;
    }

    const float dw  = __expf(-sqrtf(fmaxf(d2v, 0.f)));
    const float prx = p[jn * 3 + 0] - p[i * 3 + 0];
    const float pry = p[jn * 3 + 1] - p[i * 3 + 1];
    const float prz = p[jn * 3 + 2] - p[i * 3 + 2];
    float tt[3];
    #pragma unroll
    for (int e = 0; e < 3; ++e) {
        float v = prx * Wp1[0 * 3 + e] + pry * Wp1[1 * 3 + e] + prz * Wp1[2 * 3 + e] + bp1[e];
        v = v * (g1[e] * BN_RS) + be1[e];
        tt[e] = fmaxf(v, 0.f);
    }

    float wv8[8];
    #pragma unroll
    for (int h = 0; h < 2; ++h) {
        const int cc = c0 + h * 4;
        const float4 xk4 = h ? a1 : a0;
        const float4 xv4 = h ? b1 : b0;
        const float4 w0  = *(const float4*)&Wp2[cc];
        const float4 w1  = *(const float4*)&Wp2[128 + cc];
        const float4 w2  = *(const float4*)&Wp2[256 + cc];
        const float4 bp  = *(const float4*)&bp2[cc];
        const float4 xq4 = *(const float4*)&xqg[(size_t)i * CCH + cc];
        const float4 gg  = *(const float4*)&g2[cc];
        const float4 bb  = *(const float4*)&be2[cc];
        float4 val4;
        {
            const float pr = tt[0] * w0.x + tt[1] * w1.x + tt[2] * w2.x + bp.x;
            wv8[h * 4 + 0] = fmaxf(((xq4.x - xk4.x) + pr) * (gg.x * BN_RS) + bb.x, 0.f);
            val4.x = xv4.x * dw + pr;
        }
        {
            const float pr = tt[0] * w0.y + tt[1] * w1.y + tt[2] * w2.y + bp.y;
            wv8[h * 4 + 1] = fmaxf(((xq4.y - xk4.y) + pr) * (gg.y * BN_RS) + bb.y, 0.f);
            val4.y = xv4.y * dw + pr;
        }
        {
            const float pr = tt[0] * w0.z + tt[1] * w1.z + tt[2] * w2.z + bp.z;
            wv8[h * 4 + 2] = fmaxf(((xq4.z - xk4.z) + pr) * (gg.z * BN_RS) + bb.z, 0.f);
            val4.z = xv4.z * dw + pr;
        }
        {
            const float pr = tt[0] * w0.w + tt[1] * w1.w + tt[2] * w2.w + bp.w;
            wv8[h * 4 + 3] = fmaxf(((xq4.w - xk4.w) + pr) * (gg.w * BN_RS) + bb.w, 0.f);
            val4.w = xv4.w * dw + pr;
        }
        *(float4*)&s_val[k][cc] = val4;
    }
    __syncthreads();                                   // B0

    float pp[16];
    #pragma unroll
    for (int m = 0; m < 16; ++m) {
        const float4 a = *(const float4*)&s_w1tA[m][tl * 4];
        const float4 b = *(const float4*)&s_w1tB[m][tl * 4];
        pp[m] = wv8[0] * a.x + wv8[1] * a.y + wv8[2] * a.z + wv8[3] * a.w
              + wv8[4] * b.x + wv8[5] * b.y + wv8[6] * b.z + wv8[7] * b.w;
    }
    {
        float q8[8];
        #pragma unroll
        for (int jj = 0; jj < 8; ++jj) {
            const float send = (tl & 8) ? pp[jj] : pp[jj + 8];
            const float keep = (tl & 8) ? pp[jj + 8] : pp[jj];
            q8[jj] = keep + __shfl_xor(send, 8);
        }
        float q4[4];
        #pragma unroll
        for (int jj = 0; jj < 4; ++jj) {
            const float send = (tl & 4) ? q8[jj] : q8[jj + 4];
            const float keep = (tl & 4) ? q8[jj + 4] : q8[jj];
            q4[jj] = keep + __shfl_xor(send, 4);
        }
        float q2[2];
        #pragma unroll
        for (int jj = 0; jj < 2; ++jj) {
            const float send = (tl & 2) ? q4[jj] : q4[jj + 2];
            const float keep = (tl & 2) ? q4[jj + 2] : q4[jj];
            q2[jj] = keep + __shfl_xor(send, 2);
        }
        const float s1 = (tl & 1) ? q2[0] : q2[1];
        const float k1 = (tl & 1) ? q2[1] : q2[0];
        pp[0] = k1 + __shfl_xor(s1, 1);        // w1[k][m=tl]
    }

    const float rr = fmaxf((pp[0] + bw1m) * g3m + be3m, 0.f);

    float p2[16];
    #pragma unroll
    for (int j2 = 0; j2 < 16; ++j2) p2[j2] = rr * ww2row[j2];
    float w2v;
    {
        float q8[8];
        #pragma unroll
        for (int jj = 0; jj < 8; ++jj) {
            const float send = (tl & 8) ? p2[jj] : p2[jj + 8];
            const float keep = (tl & 8) ? p2[jj + 8] : p2[jj];
            q8[jj] = keep + __shfl_xor(send, 8);
        }
        float q4[4];
        #pragma unroll
        for (int jj = 0; jj < 4; ++jj) {
            const float send = (tl & 4) ? q8[jj] : q8[jj + 4];
            const float keep = (tl & 4) ? q8[jj + 4] : q8[jj];
            q4[jj] = keep + __shfl_xor(send, 4);
        }
        float q2[2];
        #pragma unroll
        for (int jj = 0; jj < 2; ++jj) {
            const float send = (tl & 2) ? q4[jj] : q4[jj + 2];
            const float keep = (tl & 2) ? q4[jj + 2] : q4[jj];
            q2[jj] = keep + __shfl_xor(send, 2);
        }
        const float s1 = (tl & 1) ? q2[0] : q2[1];
        const float k1 = (tl & 1) ? q2[1] : q2[0];
        w2v = k1 + __shfl_xor(s1, 1) + bw2m;   // w2[k][m2=tl]
    }
    s_w2[k][tl] = w2v;
    __syncthreads();                                   // B1

    float mx = -3.0e38f;
    #pragma unroll
    for (int mm = 0; mm < 16; ++mm) mx = fmaxf(mx, s_w2[mm][tl]);
    float ss = 0.f;
    #pragma unroll
    for (int mm = 0; mm < 16; ++mm) ss += __expf(s_w2[mm][tl] - mx);
    s_wn[k][tl] = __fdividef(__expf(w2v - mx), ss);
    __syncthreads();                                   // B2

    if (t < 128) {
        const int c = t, mc = t & 15;
        float o = 0.f;
        #pragma unroll
        for (int kk = 0; kk < 16; ++kk) o += s_val[kk][c] * s_wn[kk][mc];
        out[(size_t)i * CCH + c] = o;
    }
}

// ---------------------------------------------------------------------------
extern "C" void kernel_launch(void* const* d_in, const int* in_sizes, int n_in,
                              void* d_out, int out_size, void* d_ws, size_t ws_size,
                              hipStream_t stream) {
    (void)in_sizes; (void)n_in; (void)out_size; (void)ws_size;
    const float* p   = (const float*)d_in[0];
    const float* x   = (const float*)d_in[1];
    const float* Wq  = (const float*)d_in[2];
    const float* bq  = (const float*)d_in[3];
    const float* Wk  = (const float*)d_in[4];
    const float* bk  = (const float*)d_in[5];
    const float* Wv  = (const float*)d_in[6];
    const float* bv  = (const float*)d_in[7];
    const float* Wp1 = (const float*)d_in[8];
    const float* bp1 = (const float*)d_in[9];
    const float* g1  = (const float*)d_in[10];
    const float* be1 = (const float*)d_in[11];
    const float* Wp2 = (const float*)d_in[12];
    const float* bp2 = (const float*)d_in[13];
    const float* g2  = (const float*)d_in[14];
    const float* be2 = (const float*)d_in[15];
    const float* Ww1 = (const float*)d_in[16];
    const float* bw1 = (const float*)d_in[17];
    const float* g3  = (const float*)d_in[18];
    const float* be3 = (const float*)d_in[19];
    const float* Ww2 = (const float*)d_in[20];
    const float* bw2 = (const float*)d_in[21];
    float* out = (float*)d_out;

    // workspace layout
    char* ws = (char*)d_ws;
    int*    idxb = (int*)ws;                                   // 512 KB
    float*  d2b  = (float*)(ws + (size_t)512 * 1024);          // 512 KB
    float*  xqb  = (float*)(ws + (size_t)1 * 1024 * 1024);     // 4 MB
    float*  xkb  = (float*)(ws + (size_t)5 * 1024 * 1024);     // 4 MB
    float*  xvb  = (float*)(ws + (size_t)9 * 1024 * 1024);     // 4 MB
    float4* c4b  = (float4*)(ws + (size_t)13 * 1024 * 1024);   // 128 KB

    pack_kernel<<<dim3(NPTS / 256), dim3(256), 0, stream>>>(p, c4b);
    knn_kernel<<<dim3(NPTS / (4 * QW)), dim3(256), 0, stream>>>(c4b, idxb, d2b);
    gemm3_kernel<<<dim3(NPTS / 64, CCH / 64, 3), dim3(256), 0, stream>>>(
        x, Wq, bq, Wk, bk, Wv, bv, xqb, xkb, xvb);
    fused_kernel<<<dim3(NPTS), dim3(256), 0, stream>>>(
        p, xqb, xkb, xvb, idxb, d2b,
        Wp1, bp1, g1, be1, Wp2, bp2, g2, be2, Ww1, bw1, g3, be3, Ww2, bw2, out);
}

// Round 11
// 107.761 us; speedup vs baseline: 1.2955x; 1.0277x over previous
//
#include <hip/hip_runtime.h>
#include <math.h>

// Problem constants (fixed-shape problem)
#define NPTS 8192
#define CCH  128
#define KNN  16
#define BN_RS 0.9999950000374997f   // 1/sqrt(1 + 1e-5)

typedef unsigned long long u64;
typedef unsigned short u16;

__device__ __forceinline__ u16 f2bf(float f) {   // round-to-nearest-even
    unsigned u = __float_as_uint(f);
    u += 0x7FFFu + ((u >> 16) & 1u);
    return (u16)(u >> 16);
}

__device__ __forceinline__ void bf8_to_f(const uint4 u, float* f) {
    f[0] = __uint_as_float(u.x << 16); f[1] = __uint_as_float(u.x & 0xffff0000u);
    f[2] = __uint_as_float(u.y << 16); f[3] = __uint_as_float(u.y & 0xffff0000u);
    f[4] = __uint_as_float(u.z << 16); f[5] = __uint_as_float(u.z & 0xffff0000u);
    f[6] = __uint_as_float(u.w << 16); f[7] = __uint_as_float(u.w & 0xffff0000u);
}

// ---------------------------------------------------------------------------
// Kernel P: pack candidate points as float4 (x, y, z, |p|^2)
// ---------------------------------------------------------------------------
__global__ __launch_bounds__(256) void pack_kernel(const float* __restrict__ p,
                                                   float4* __restrict__ c4) {
    const int j = blockIdx.x * 256 + threadIdx.x;
    if (j < NPTS) {
        const float x = p[3 * j + 0], y = p[3 * j + 1], z = p[3 * j + 2];
        c4[j] = make_float4(x, y, z, x * x + y * y + z * z);
    }
}

// ---------------------------------------------------------------------------
// Kernel A: KNN via sampled-threshold 1.25-pass select (R9 version, verbatim).
// ---------------------------------------------------------------------------
#define QW    2
#define CAP   104
#define TILE  1024
#define SAMPN 4096

__device__ __forceinline__ u64 bitonic64(u64 v, const int lane) {
    #pragma unroll
    for (int k = 2; k <= 64; k <<= 1) {
        #pragma unroll
        for (int j = k >> 1; j > 0; j >>= 1) {
            const u64  o       = __shfl_xor(v, j);
            const bool takemin = (((lane & j) == 0) == ((lane & k) == 0));
            v = ((o < v) == takemin) ? o : v;
        }
    }
    return v;
}

__device__ __forceinline__ float bitonicf(float v, const int lane) {
    #pragma unroll
    for (int k = 2; k <= 64; k <<= 1) {
        #pragma unroll
        for (int j = k >> 1; j > 0; j >>= 1) {
            const float o      = __shfl_xor(v, j);
            const bool takemin = (((lane & j) == 0) == ((lane & k) == 0));
            v = ((o < v) == takemin) ? o : v;
        }
    }
    return v;
}

__device__ __forceinline__ float make_d2(const float4 c, const float m2x, const float m2y,
                                         const float m2z, const float qb) {
    float d2 = fmaf(m2x, c.x, fmaf(m2y, c.y, fmaf(m2z, c.z, c.w + qb)));
    return fmaxf(d2, 0.0f);
}

__global__ __launch_bounds__(256) void knn_kernel(const float4* __restrict__ c4,
                                                  int* __restrict__ oidx,
                                                  float* __restrict__ od2) {
    __shared__ float4 s_pt[TILE];            // 16 KB
    __shared__ u64    s_col[4][QW][CAP];     // 6.5 KB
    __shared__ int    s_cnt[4][QW];

    const int t     = threadIdx.x;
    const int wave  = t >> 6;
    const int lane  = t & 63;
    const int qbase = (blockIdx.x * 4 + wave) * QW;

    float m2x[QW], m2y[QW], m2z[QW], qb[QW];
    #pragma unroll
    for (int qi = 0; qi < QW; ++qi) {
        const float4 q = c4[qbase + qi];
        m2x[qi] = -2.0f * q.x;
        m2y[qi] = -2.0f * q.y;
        m2z[qi] = -2.0f * q.z;
        qb[qi]  = q.w;
    }
    if (lane < QW) s_cnt[wave][lane] = 0;

    float bd[QW];
    #pragma unroll
    for (int qi = 0; qi < QW; ++qi) bd[qi] = 3.0e38f;

    for (int l = lane; l < SAMPN; l += 128) {
        const float4 c0 = c4[l];
        const float4 c1 = c4[l + 64];
        #pragma unroll
        for (int qi = 0; qi < QW; ++qi) {
            const float d0 = make_d2(c0, m2x[qi], m2y[qi], m2z[qi], qb[qi]);
            const float d1 = make_d2(c1, m2x[qi], m2y[qi], m2z[qi], qb[qi]);
            bd[qi] = fminf(bd[qi], fminf(d0, d1));
        }
    }

    float tauf[QW];
    #pragma unroll
    for (int qi = 0; qi < QW; ++qi) {
        const float s = bitonicf(bd[qi], lane);
        tauf[qi] = __shfl(s, 15);
    }

    for (int tb = 0; tb < NPTS; tb += TILE) {
        __syncthreads();
        for (int jj = t; jj < TILE; jj += 256) s_pt[jj] = c4[tb + jj];
        __syncthreads();
        for (int l = lane; l < TILE; l += 128) {
            const float4 c0 = s_pt[l];
            const float4 c1 = s_pt[l + 64];
            const int j0 = tb + l, j1 = tb + l + 64;
            #pragma unroll
            for (int qi = 0; qi < QW; ++qi) {
                const float d0 = make_d2(c0, m2x[qi], m2y[qi], m2z[qi], qb[qi]);
                const float d1 = make_d2(c1, m2x[qi], m2y[qi], m2z[qi], qb[qi]);
                if (d0 <= tauf[qi]) {
                    const int pos = atomicAdd(&s_cnt[wave][qi], 1);
                    if (pos < CAP)
                        s_col[wave][qi][pos] = ((u64)__float_as_uint(d0) << 32) | (u64)(unsigned)j0;
                }
                if (d1 <= tauf[qi]) {
                    const int pos = atomicAdd(&s_cnt[wave][qi], 1);
                    if (pos < CAP)
                        s_col[wave][qi][pos] = ((u64)__float_as_uint(d1) << 32) | (u64)(unsigned)j1;
                }
            }
        }
    }

    #pragma unroll 1
    for (int qi = 0; qi < QW; ++qi) {
        const int q = qbase + qi;
        int M = s_cnt[wave][qi];

        if (M > CAP) {
            float fb = 3.0e38f;
            for (int l = lane; l < NPTS; l += 64)
                fb = fminf(fb, make_d2(c4[l], m2x[qi], m2y[qi], m2z[qi], qb[qi]));
            const float s    = bitonicf(fb, lane);
            const float tau2 = __shfl(s, 15);
            if (lane == 0) s_cnt[wave][qi] = 0;
            for (int l = lane; l < NPTS; l += 64) {
                const float d = make_d2(c4[l], m2x[qi], m2y[qi], m2z[qi], qb[qi]);
                if (d <= tau2) {
                    const int pos = atomicAdd(&s_cnt[wave][qi], 1);
                    if (pos < CAP)
                        s_col[wave][qi][pos] = ((u64)__float_as_uint(d) << 32) | (u64)(unsigned)l;
                }
            }
            M = s_cnt[wave][qi];
            if (M > CAP) M = CAP;
        }

        if (M <= 64) {
            u64 v = (lane < M) ? s_col[wave][qi][lane] : ~0ull;
            v = bitonic64(v, lane);
            if (lane < KNN) {
                oidx[q * KNN + lane] = (int)(v & 0xffffffffu);
                od2 [q * KNN + lane] = __uint_as_float((unsigned)(v >> 32));
            }
        } else {
            u64 a = (lane < M) ? s_col[wave][qi][lane] : ~0ull;
            a = bitonic64(a, lane);
            u64 b = (lane + 64 < M) ? s_col[wave][qi][lane + 64] : ~0ull;
            b = bitonic64(b, lane);
            const u64 bs = __shfl(b, lane & 15);
            u64 mv = (lane < 16) ? a : ((lane < 32) ? bs : ~0ull);
            mv = bitonic64(mv, lane);
            if (lane < KNN) {
                oidx[q * KNN + lane] = (int)(mv & 0xffffffffu);
                od2 [q * KNN + lane] = __uint_as_float((unsigned)(mv >> 32));
            }
        }
    }
}

// ---------------------------------------------------------------------------
// Kernel B: three fp32 GEMMs; xq written fp32, xk/xv written bf16 (RNE).
// bf16 halves the fused kernel's random-gather working set (8 MB -> 4 MB,
// fitting one XCD's 4 MB L2) and halves gather bytes.
// ---------------------------------------------------------------------------
__global__ __launch_bounds__(256) void gemm3_kernel(
    const float* __restrict__ x,
    const float* __restrict__ Wq, const float* __restrict__ bq,
    const float* __restrict__ Wk, const float* __restrict__ bk,
    const float* __restrict__ Wv, const float* __restrict__ bv,
    float* __restrict__ xq, u16* __restrict__ xk16, u16* __restrict__ xv16) {
    const int which = blockIdx.z;
    const float* W    = (which == 0) ? Wq : (which == 1) ? Wk : Wv;
    const float* bias = (which == 0) ? bq : (which == 1) ? bk : bv;

    const int row0 = blockIdx.x * 64;
    const int col0 = blockIdx.y * 64;

    __shared__ float As[64][68];
    __shared__ float Bs[64][68];

    const int t  = threadIdx.x;
    const int lr = t >> 4;
    const int lc = t & 15;
    const int or0 = (t >> 4) * 4;
    const int oc0 = (t & 15) * 4;

    float acc[4][4] = {};

    for (int kk = 0; kk < CCH; kk += 64) {
        __syncthreads();
        #pragma unroll
        for (int i = 0; i < 4; ++i) {
            const int r = lr + i * 16;
            *(float4*)&As[r][lc * 4] =
                *(const float4*)&x[(size_t)(row0 + r) * CCH + kk + lc * 4];
            *(float4*)&Bs[r][lc * 4] =
                *(const float4*)&W[(size_t)(kk + r) * CCH + col0 + lc * 4];
        }
        __syncthreads();
        #pragma unroll 8
        for (int k = 0; k < 64; ++k) {
            const float a0 = As[or0 + 0][k];
            const float a1 = As[or0 + 1][k];
            const float a2 = As[or0 + 2][k];
            const float a3 = As[or0 + 3][k];
            const float4 b = *(const float4*)&Bs[k][oc0];
            acc[0][0] += a0 * b.x; acc[0][1] += a0 * b.y; acc[0][2] += a0 * b.z; acc[0][3] += a0 * b.w;
            acc[1][0] += a1 * b.x; acc[1][1] += a1 * b.y; acc[1][2] += a1 * b.z; acc[1][3] += a1 * b.w;
            acc[2][0] += a2 * b.x; acc[2][1] += a2 * b.y; acc[2][2] += a2 * b.z; acc[2][3] += a2 * b.w;
            acc[3][0] += a3 * b.x; acc[3][1] += a3 * b.y; acc[3][2] += a3 * b.z; acc[3][3] += a3 * b.w;
        }
    }

    const float4 bb = *(const float4*)&bias[col0 + oc0];
    if (which == 0) {
        #pragma unroll
        for (int i = 0; i < 4; ++i) {
            const int r = row0 + or0 + i;
            float4 o;
            o.x = acc[i][0] + bb.x;
            o.y = acc[i][1] + bb.y;
            o.z = acc[i][2] + bb.z;
            o.w = acc[i][3] + bb.w;
            *(float4*)&xq[(size_t)r * CCH + col0 + oc0] = o;
        }
    } else {
        u16* o16 = (which == 1) ? xk16 : xv16;
        #pragma unroll
        for (int i = 0; i < 4; ++i) {
            const int r = row0 + or0 + i;
            ushort4 h;
            h.x = f2bf(acc[i][0] + bb.x);
            h.y = f2bf(acc[i][1] + bb.y);
            h.z = f2bf(acc[i][2] + bb.z);
            h.w = f2bf(acc[i][3] + bb.w);
            *(ushort4*)&o16[(size_t)r * CCH + col0 + oc0] = h;
        }
    }
}

// ---------------------------------------------------------------------------
// Kernel C: fused per-point attention, v7 = v6 + bf16 xk/xv gathers.
// Gather loads: 2x uint4 (16B) per thread instead of 4x float4 (32B).
// ---------------------------------------------------------------------------
__global__ __launch_bounds__(256) void fused_kernel(
    const float* __restrict__ p,
    const float* __restrict__ xqg, const u16* __restrict__ xkg, const u16* __restrict__ xvg,
    const int* __restrict__ nidx, const float* __restrict__ nd2,
    const float* __restrict__ Wp1, const float* __restrict__ bp1,
    const float* __restrict__ g1,  const float* __restrict__ be1,
    const float* __restrict__ Wp2, const float* __restrict__ bp2,
    const float* __restrict__ g2,  const float* __restrict__ be2,
    const float* __restrict__ Ww1, const float* __restrict__ bw1,
    const float* __restrict__ g3,  const float* __restrict__ be3,
    const float* __restrict__ Ww2, const float* __restrict__ bw2,
    float* __restrict__ out) {
    const int i = blockIdx.x;
    const int t = threadIdx.x;

    __shared__ float s_w1tA[16][66];
    __shared__ float s_w1tB[16][66];
    __shared__ float s_val[16][132];
    __shared__ float s_w2[16][17];
    __shared__ float s_wn[16][17];

    const int k  = t >> 4;
    const int tl = t & 15;
    const int c0 = tl * 8;

    // ---- issue long-latency loads first ----
    const int   jn  = nidx[i * KNN + k];
    const float d2v = nd2[i * KNN + k];
    const uint4 ku = *(const uint4*)&xkg[(size_t)jn * CCH + c0];   // 8 bf16
    const uint4 vu = *(const uint4*)&xvg[(size_t)jn * CCH + c0];   // 8 bf16

    float ww2row[16];
    {
        const float4 r0 = *(const float4*)&Ww2[tl * 16 + 0];
        const float4 r1 = *(const float4*)&Ww2[tl * 16 + 4];
        const float4 r2 = *(const float4*)&Ww2[tl * 16 + 8];
        const float4 r3 = *(const float4*)&Ww2[tl * 16 + 12];
        ww2row[0]=r0.x; ww2row[1]=r0.y; ww2row[2]=r0.z; ww2row[3]=r0.w;
        ww2row[4]=r1.x; ww2row[5]=r1.y; ww2row[6]=r1.z; ww2row[7]=r1.w;
        ww2row[8]=r2.x; ww2row[9]=r2.y; ww2row[10]=r2.z; ww2row[11]=r2.w;
        ww2row[12]=r3.x; ww2row[13]=r3.y; ww2row[14]=r3.z; ww2row[15]=r3.w;
    }
    const float bw1m = bw1[tl];
    const float g3m  = g3[tl] * BN_RS;
    const float be3m = be3[tl];
    const float bw2m = bw2[tl];

    #pragma unroll
    for (int j = 0; j < 8; ++j) {
        const int e2   = t + j * 256;
        const int m    = e2 & 15;
        const int csrc = e2 >> 4;
        const int col  = ((csrc >> 3) << 2) | (csrc & 3);
        const float v  = Ww1[e2];
        if (csrc & 4) s_w1tB[m][col] = v;
        else          s_w1tA[m][col] = v;
    }

    const float dw  = __expf(-sqrtf(fmaxf(d2v, 0.f)));
    const float prx = p[jn * 3 + 0] - p[i * 3 + 0];
    const float pry = p[jn * 3 + 1] - p[i * 3 + 1];
    const float prz = p[jn * 3 + 2] - p[i * 3 + 2];
    float tt[3];
    #pragma unroll
    for (int e = 0; e < 3; ++e) {
        float v = prx * Wp1[0 * 3 + e] + pry * Wp1[1 * 3 + e] + prz * Wp1[2 * 3 + e] + bp1[e];
        v = v * (g1[e] * BN_RS) + be1[e];
        tt[e] = fmaxf(v, 0.f);
    }

    float xk8[8], xv8[8];
    bf8_to_f(ku, xk8);
    bf8_to_f(vu, xv8);

    float wv8[8];
    #pragma unroll
    for (int h = 0; h < 2; ++h) {
        const int cc = c0 + h * 4;
        const float4 w0  = *(const float4*)&Wp2[cc];
        const float4 w1  = *(const float4*)&Wp2[128 + cc];
        const float4 w2  = *(const float4*)&Wp2[256 + cc];
        const float4 bp  = *(const float4*)&bp2[cc];
        const float4 xq4 = *(const float4*)&xqg[(size_t)i * CCH + cc];
        const float4 gg  = *(const float4*)&g2[cc];
        const float4 bb  = *(const float4*)&be2[cc];
        float4 val4;
        {
            const float pr = tt[0] * w0.x + tt[1] * w1.x + tt[2] * w2.x + bp.x;
            wv8[h * 4 + 0] = fmaxf(((xq4.x - xk8[h * 4 + 0]) + pr) * (gg.x * BN_RS) + bb.x, 0.f);
            val4.x = xv8[h * 4 + 0] * dw + pr;
        }
        {
            const float pr = tt[0] * w0.y + tt[1] * w1.y + tt[2] * w2.y + bp.y;
            wv8[h * 4 + 1] = fmaxf(((xq4.y - xk8[h * 4 + 1]) + pr) * (gg.y * BN_RS) + bb.y, 0.f);
            val4.y = xv8[h * 4 + 1] * dw + pr;
        }
        {
            const float pr = tt[0] * w0.z + tt[1] * w1.z + tt[2] * w2.z + bp.z;
            wv8[h * 4 + 2] = fmaxf(((xq4.z - xk8[h * 4 + 2]) + pr) * (gg.z * BN_RS) + bb.z, 0.f);
            val4.z = xv8[h * 4 + 2] * dw + pr;
        }
        {
            const float pr = tt[0] * w0.w + tt[1] * w1.w + tt[2] * w2.w + bp.w;
            wv8[h * 4 + 3] = fmaxf(((xq4.w - xk8[h * 4 + 3]) + pr) * (gg.w * BN_RS) + bb.w, 0.f);
            val4.w = xv8[h * 4 + 3] * dw + pr;
        }
        *(float4*)&s_val[k][cc] = val4;
    }
    __syncthreads();                                   // B0

    float pp[16];
    #pragma unroll
    for (int m = 0; m < 16; ++m) {
        const float4 a = *(const float4*)&s_w1tA[m][tl * 4];
        const float4 b = *(const float4*)&s_w1tB[m][tl * 4];
        pp[m] = wv8[0] * a.x + wv8[1] * a.y + wv8[2] * a.z + wv8[3] * a.w
              + wv8[4] * b.x + wv8[5] * b.y + wv8[6] * b.z + wv8[7] * b.w;
    }
    {
        float q8[8];
        #pragma unroll
        for (int jj = 0; jj < 8; ++jj) {
            const float send = (tl & 8) ? pp[jj] : pp[jj + 8];
            const float keep = (tl & 8) ? pp[jj + 8] : pp[jj];
            q8[jj] = keep + __shfl_xor(send, 8);
        }
        float q4[4];
        #pragma unroll
        for (int jj = 0; jj < 4; ++jj) {
            const float send = (tl & 4) ? q8[jj] : q8[jj + 4];
            const float keep = (tl & 4) ? q8[jj + 4] : q8[jj];
            q4[jj] = keep + __shfl_xor(send, 4);
        }
        float q2[2];
        #pragma unroll
        for (int jj = 0; jj < 2; ++jj) {
            const float send = (tl & 2) ? q4[jj] : q4[jj + 2];
            const float keep = (tl & 2) ? q4[jj + 2] : q4[jj];
            q2[jj] = keep + __shfl_xor(send, 2);
        }
        const float s1 = (tl & 1) ? q2[0] : q2[1];
        const float k1 = (tl & 1) ? q2[1] : q2[0];
        pp[0] = k1 + __shfl_xor(s1, 1);        // w1[k][m=tl]
    }

    const float rr = fmaxf((pp[0] + bw1m) * g3m + be3m, 0.f);

    float p2[16];
    #pragma unroll
    for (int j2 = 0; j2 < 16; ++j2) p2[j2] = rr * ww2row[j2];
    float w2v;
    {
        float q8[8];
        #pragma unroll
        for (int jj = 0; jj < 8; ++jj) {
            const float send = (tl & 8) ? p2[jj] : p2[jj + 8];
            const float keep = (tl & 8) ? p2[jj + 8] : p2[jj];
            q8[jj] = keep + __shfl_xor(send, 8);
        }
        float q4[4];
        #pragma unroll
        for (int jj = 0; jj < 4; ++jj) {
            const float send = (tl & 4) ? q8[jj] : q8[jj + 4];
            const float keep = (tl & 4) ? q8[jj + 4] : q8[jj];
            q4[jj] = keep + __shfl_xor(send, 4);
        }
        float q2[2];
        #pragma unroll
        for (int jj = 0; jj < 2; ++jj) {
            const float send = (tl & 2) ? q4[jj] : q4[jj + 2];
            const float keep = (tl & 2) ? q4[jj + 2] : q4[jj];
            q2[jj] = keep + __shfl_xor(send, 2);
        }
        const float s1 = (tl & 1) ? q2[0] : q2[1];
        const float k1 = (tl & 1) ? q2[1] : q2[0];
        w2v = k1 + __shfl_xor(s1, 1) + bw2m;   // w2[k][m2=tl]
    }
    s_w2[k][tl] = w2v;
    __syncthreads();                                   // B1

    float mx = -3.0e38f;
    #pragma unroll
    for (int mm = 0; mm < 16; ++mm) mx = fmaxf(mx, s_w2[mm][tl]);
    float ss = 0.f;
    #pragma unroll
    for (int mm = 0; mm < 16; ++mm) ss += __expf(s_w2[mm][tl] - mx);
    s_wn[k][tl] = __fdividef(__expf(w2v - mx), ss);
    __syncthreads();                                   // B2

    if (t < 128) {
        const int c = t, mc = t & 15;
        float o = 0.f;
        #pragma unroll
        for (int kk = 0; kk < 16; ++kk) o += s_val[kk][c] * s_wn[kk][mc];
        out[(size_t)i * CCH + c] = o;
    }
}

// ---------------------------------------------------------------------------
extern "C" void kernel_launch(void* const* d_in, const int* in_sizes, int n_in,
                              void* d_out, int out_size, void* d_ws, size_t ws_size,
                              hipStream_t stream) {
    (void)in_sizes; (void)n_in; (void)out_size; (void)ws_size;
    const float* p   = (const float*)d_in[0];
    const float* x   = (const float*)d_in[1];
    const float* Wq  = (const float*)d_in[2];
    const float* bq  = (const float*)d_in[3];
    const float* Wk  = (const float*)d_in[4];
    const float* bk  = (const float*)d_in[5];
    const float* Wv  = (const float*)d_in[6];
    const float* bv  = (const float*)d_in[7];
    const float* Wp1 = (const float*)d_in[8];
    const float* bp1 = (const float*)d_in[9];
    const float* g1  = (const float*)d_in[10];
    const float* be1 = (const float*)d_in[11];
    const float* Wp2 = (const float*)d_in[12];
    const float* bp2 = (const float*)d_in[13];
    const float* g2  = (const float*)d_in[14];
    const float* be2 = (const float*)d_in[15];
    const float* Ww1 = (const float*)d_in[16];
    const float* bw1 = (const float*)d_in[17];
    const float* g3  = (const float*)d_in[18];
    const float* be3 = (const float*)d_in[19];
    const float* Ww2 = (const float*)d_in[20];
    const float* bw2 = (const float*)d_in[21];
    float* out = (float*)d_out;

    // workspace layout
    char* ws = (char*)d_ws;
    int*    idxb  = (int*)ws;                                   // 512 KB
    float*  d2b   = (float*)(ws + (size_t)512 * 1024);          // 512 KB
    float*  xqb   = (float*)(ws + (size_t)1 * 1024 * 1024);     // 4 MB
    u16*    xkb16 = (u16*)(ws + (size_t)5 * 1024 * 1024);       // 2 MB
    u16*    xvb16 = (u16*)(ws + (size_t)7 * 1024 * 1024);       // 2 MB
    float4* c4b   = (float4*)(ws + (size_t)9 * 1024 * 1024);    // 128 KB

    pack_kernel<<<dim3(NPTS / 256), dim3(256), 0, stream>>>(p, c4b);
    knn_kernel<<<dim3(NPTS / (4 * QW)), dim3(256), 0, stream>>>(c4b, idxb, d2b);
    gemm3_kernel<<<dim3(NPTS / 64, CCH / 64, 3), dim3(256), 0, stream>>>(
        x, Wq, bq, Wk, bk, Wv, bv, xqb, xkb16, xvb16);
    fused_kernel<<<dim3(NPTS), dim3(256), 0, stream>>>(
        p, xqb, xkb16, xvb16, idxb, d2b,
        Wp1, bp1, g1, be1, Wp2, bp2, g2, be2, Ww1, bw1, g3, be3, Ww2, bw2, out);
}